// Round 12
// baseline (344.005 us; speedup 1.0000x reference)
//
#include <hip/hip_runtime.h>
#include <hip/hip_bf16.h>
#include <math.h>

#define NN   29040
#define NLAT 121
#define NLON 240
#define HD   128
#define LVN  11
#define EE   464640

typedef __attribute__((ext_vector_type(8))) short short8;
typedef __attribute__((ext_vector_type(16))) float f16v;

// packed-weight offsets (in shorts) inside wp buffer
#define OFF_WE1 0          // 20 kf x 4 nf  = 80 frags (1 KB each)
#define OFF_WE2 40960      // 8 x 4 = 32
#define OFF_WC1 57344      // 8 x 4 = 32
#define OFF_WCL 73728      // 8 x 1 = 8
#define OFF_WN1 77824      // 24 x 4 = 96
#define OFF_WN2 126976     // 8 x 4 = 32
#define WP_SHORTS 143360

__device__ inline short f2b(float x) {
    union { __hip_bfloat16 b; short s; } v;
    v.b = __float2bfloat16(x);
    return v.s;
}
__device__ inline float b2f(unsigned short b) {
    union { unsigned u; float f; } v; v.u = ((unsigned)b) << 16;
    return v.f;
}

// ================= fused setup: hist | h-cast | uv-prep | weight-pack =================
#define SB_HIST  1815
#define SB_HCAST 1815
#define SB_UV    114
#define SB_WP    70

__global__ __launch_bounds__(256)
void setup_kernel(const int* __restrict__ eidx, int* __restrict__ cnt,
                  const float* __restrict__ h, short* __restrict__ hb,
                  const float* __restrict__ u, const float* __restrict__ v,
                  float* __restrict__ uvrec,
                  const float* __restrict__ We1, const float* __restrict__ We2,
                  const float* __restrict__ Wc1, const float* __restrict__ Wcl,
                  const float* __restrict__ Wn1, const float* __restrict__ Wn2,
                  short* __restrict__ wp)
{
    const int b = blockIdx.x, tid = threadIdx.x;
    if (b < SB_HIST) {
        int e = b * 256 + tid;
        atomicAdd(&cnt[eidx[e]], 1);
        return;
    }
    if (b < SB_HIST + SB_HCAST) {
        int idx = (b - SB_HIST) * 256 + tid;          // 8 elems each
        const float4* hf = (const float4*)h;
        float4 a = hf[idx * 2], c = hf[idx * 2 + 1];
        short8 o;
        o[0] = f2b(a.x); o[1] = f2b(a.y); o[2] = f2b(a.z); o[3] = f2b(a.w);
        o[4] = f2b(c.x); o[5] = f2b(c.y); o[6] = f2b(c.z); o[7] = f2b(c.w);
        ((short8*)hb)[idx] = o;
        return;
    }
    if (b < SB_HIST + SB_HCAST + SB_UV) {
        int n = (b - SB_HIST - SB_HCAST) * 256 + tid;
        if (n >= NN) return;
        float* r = uvrec + (size_t)n * 36;
        float un = 0.f, vn = 0.f;
#pragma unroll
        for (int l = 0; l < LVN; ++l) {
            float uu = u[n * LVN + l], vv = v[n * LVN + l];
            float s = sqrtf(uu * uu + vv * vv);
            r[l]      = uu / s;
            r[11 + l] = vv / s;
            r[22 + l] = s;
            un += uu * uu; vn += vv * vv;
        }
        r[33] = sqrtf(un);
        r[34] = sqrtf(vn);
        r[35] = 0.f;
        return;
    }
    // ---- weight pack for 32x32x16 MFMA B-fragments ----
    // lane l, elem i -> k = kf*16 + 8*(l>>5) + i ; n = nf*32 + (l&31)
    {
        int fg = (b - SB_HIST - SB_HCAST - SB_UV) * 4 + (tid >> 6);   // 0..279
        const int l = tid & 63;
        int kind, f, base;
        if (fg < 80)       { kind = 0; f = fg;       base = OFF_WE1; }   // 20x4
        else if (fg < 112) { kind = 1; f = fg - 80;  base = OFF_WE2; }   // 8x4
        else if (fg < 144) { kind = 2; f = fg - 112; base = OFF_WC1; }   // 8x4
        else if (fg < 152) { kind = 3; f = fg - 144; base = OFF_WCL; }   // 8x1
        else if (fg < 248) { kind = 4; f = fg - 152; base = OFF_WN1; }   // 24x4
        else               { kind = 5; f = fg - 248; base = OFF_WN2; }   // 8x4
        const int nfw = (kind == 3) ? 1 : 4;
        const int kf = f / nfw, nf = f % nfw;
        short* dst = wp + base + (size_t)f * 512 + l * 8;
        for (int i = 0; i < 8; ++i) {
            int k = kf * 16 + ((l >> 5) << 3) + i;
            int n = nf * 32 + (l & 31);
            float val = 0.f;
            if (kind == 0) {
                int r = (k < 33) ? (256 + k) : (k == 33 ? 289 : (k < 64 ? -1 : k - 64));
                if (r >= 0) val = We1[r * HD + n];
            } else if (kind == 1) val = We2[k * HD + n];
            else if (kind == 2)  val = Wc1[k * HD + n];
            else if (kind == 3)  { if (n < 22) val = Wcl[k * 22 + n]; }
            else if (kind == 4)  val = Wn1[k * HD + n];
            else                 val = Wn2[k * HD + n];
            dst[i] = f2b(val);
        }
    }
}

// ================= CSR scan + scatter =================
__global__ __launch_bounds__(1024)
void scan_kernel(const int* __restrict__ cnt, int* __restrict__ off)
{
    __shared__ int part[1024];
    const int tid = threadIdx.x;
    const int CH = 29;
    int lo = tid * CH, hi = min(lo + CH, NN);
    int s = 0;
    for (int i = lo; i < hi; ++i) s += cnt[i];
    part[tid] = s;
    __syncthreads();
    for (int d = 1; d < 1024; d <<= 1) {
        int vv = (tid >= d) ? part[tid - d] : 0;
        __syncthreads();
        part[tid] += vv;
        __syncthreads();
    }
    int run = (tid == 0) ? 0 : part[tid - 1];
    for (int i = lo; i < hi; ++i) { off[i] = run; run += cnt[i]; }
    if (tid == 1023) off[NN] = run;
}

__global__ __launch_bounds__(256)
void scatter_kernel(const int* __restrict__ eidx, const int* __restrict__ off,
                    int* __restrict__ cur, int* __restrict__ csr)
{
    int e = blockIdx.x * 256 + threadIdx.x;
    if (e >= EE) return;
    int row = eidx[e];
    int p = atomicAdd(&cur[row], 1);
    csr[off[row] + p] = e;
}

// ================= 32x32x16 GEMM helpers =================
// A row = mrow (lane&31 within row-group), k = kf*16 + 8*(lane>>5) + i.
// C: col = lane&31, row = (reg&3) + 8*(reg>>2) + 4*(lane>>5)   [HW-verified m74/m101]
template<int KF, int NFL, int NJ>
__device__ inline void gemm32_lds(const short* At, const short* Wp, int nf0,
                                  const float* bias, f16v* acc,
                                  int mrow, int colbase, int r31, int kh, int lane)
{
    const char* arow = (const char*)At + mrow * 256;
    const int sw = (mrow & 7) << 4;
#pragma unroll
    for (int j = 0; j < NJ; ++j) {
        float bv = bias ? bias[colbase + j * 32 + r31] : 0.f;
#pragma unroll
        for (int q = 0; q < 16; ++q) acc[j][q] = bv;
    }
#pragma unroll
    for (int kf = 0; kf < KF; ++kf) {
        short8 a = *(const short8*)(arow + ((kf * 32 + 16 * kh) ^ sw));
#pragma unroll
        for (int j = 0; j < NJ; ++j) {
            short8 bfr = *(const short8*)(Wp + (size_t)(kf * NFL + nf0 + j) * 512 + lane * 8);
            acc[j] = __builtin_amdgcn_mfma_f32_32x32x16_bf16(a, bfr, acc[j], 0, 0, 0);
        }
    }
}

// store C (optionally relu) as bf16 row-major tile, 256B rows, XOR-swizzled
template<int NJ>
__device__ inline void store32(short* tile, const f16v* acc, int rg, int colbase,
                               int r31, int kh, bool relu)
{
#pragma unroll
    for (int j = 0; j < NJ; ++j)
#pragma unroll
        for (int reg = 0; reg < 16; ++reg) {
            int row = rg * 32 + (reg & 3) + 8 * (reg >> 2) + 4 * kh;
            int cb2 = (colbase + j * 32 + r31) * 2;
            float vv = acc[j][reg];
            if (relu) vv = fmaxf(vv, 0.f);
            *(short*)((char*)tile + row * 256 + (cb2 ^ ((row & 7) << 4))) = f2b(vv);
        }
}

// ================= edge kernel: 64-edge tiles, 32x32x16 MFMA =================
// (256,5): the r10 config measured 40% occupancy = 4 waves/SIMD — the 128-reg
// bucket was the cap (64 VGPR + 32 AGPR = 96 regs actually needed). Declaring
// 5 waves/EU forces the allocator into the 102-reg bucket (96 fits, no spill)
// and lets HW run 5 blocks/CU (LDS 5x25.6=128KB <= 160). r10 vs r11 measured
// that waves/CU, not weight traffic, is the binding constraint.
__global__ __launch_bounds__(256, 5)
void edge_mfma(const short* __restrict__ hb, const float* __restrict__ uvrec,
               const float* __restrict__ ea,
               const float* __restrict__ be1, const float* __restrict__ be2,
               const float* __restrict__ bc1,
               const short* __restrict__ wp,
               const int* __restrict__ eidx, const int* __restrict__ csr,
               float* __restrict__ agg, float* __restrict__ aggu,
               float* __restrict__ aggv)
{
    __shared__ short Twd[64 * 64];     // 8 KB wd tile (128B rows); later O22 f32 overlay
    __shared__ short T1[64 * 128];     // 16 KB tile (256B rows)
    __shared__ int   rows_s[64];
    __shared__ float radu_s[64], radv_s[64];

    const int tid = threadIdx.x, lane = tid & 63, w = tid >> 6;
    const int rg = w >> 1, cg = w & 1;
    const int e0 = blockIdx.x * 64;
    const int r31 = lane & 31, kh = lane >> 5;
    const int mrow = rg * 32 + r31;
    const int sw = (mrow & 7) << 4;
    const int colbase = cg * 64;

    // own-row gather pointers (early issue; csr->eidx chain overlaps wd build)
    int e1 = csr[e0 + mrow];
    int rowm = eidx[e1], colm = eidx[EE + e1];
    const short* hr = hb + (size_t)rowm * HD + 8 * kh;
    const short* hc = hb + (size_t)colm * HD + 8 * kh;

    // ---- wd tile build (block-wide, 4 threads per row) ----
    {
        const int m2 = tid >> 2, q = tid & 3;
        const int sw2 = (m2 & 7) << 4;
        int e2 = csr[e0 + m2];
        int row2 = eidx[e2], col2 = eidx[EE + e2];
        const float* rc = uvrec + (size_t)col2 * 36;
        const float* rr = uvrec + (size_t)row2 * 36;
        char* arow = (char*)(Twd + m2 * 64);
        short8 z = {0, 0, 0, 0, 0, 0, 0, 0};
        *(short8*)(arow + q * 32) = z;
        *(short8*)(arow + q * 32 + 16) = z;
        for (int l = q; l < LVN; l += 4) {
            float rel = rc[l] * rr[l] + rc[11 + l] * rr[11 + l];
            *(short*)(arow + ((2 * l) ^ sw2))        = f2b(rel);
            *(short*)(arow + ((2 * (11 + l)) ^ sw2)) = f2b(rc[22 + l]);
            *(short*)(arow + ((2 * (22 + l)) ^ sw2)) = f2b(rr[22 + l]);
        }
        if (q == 0) { rows_s[m2] = row2; radu_s[m2] = rc[33]; radv_s[m2] = rc[34]; }
        if (q == 3) *(short*)(arow + ((2 * 33) ^ sw2)) = f2b(ea[e2]);
    }
    __syncthreads();   // B1: Twd/rows_s/rad visible

    // ==== edge MLP layer 1: A = [wd(k 0..63) | h_row(64..191) | h_col(192..319)] ====
    f16v acc[2];
#pragma unroll
    for (int j = 0; j < 2; ++j) {
        float bv = be1[colbase + j * 32 + r31];
#pragma unroll
        for (int q = 0; q < 16; ++q) acc[j][q] = bv;
    }
    {
        const char* awd = (const char*)(Twd + mrow * 64);
#pragma unroll
        for (int kf = 0; kf < 4; ++kf) {
            short8 a = *(const short8*)(awd + ((kf * 32 + 16 * kh) ^ sw));
#pragma unroll
            for (int j = 0; j < 2; ++j) {
                short8 bfr = *(const short8*)(wp + OFF_WE1 + (size_t)(kf * 4 + cg * 2 + j) * 512 + lane * 8);
                acc[j] = __builtin_amdgcn_mfma_f32_32x32x16_bf16(a, bfr, acc[j], 0, 0, 0);
            }
        }
#pragma unroll
        for (int s = 0; s < 8; ++s) {
            short8 a = *(const short8*)(hr + s * 16);
#pragma unroll
            for (int j = 0; j < 2; ++j) {
                short8 bfr = *(const short8*)(wp + OFF_WE1 + (size_t)((s + 4) * 4 + cg * 2 + j) * 512 + lane * 8);
                acc[j] = __builtin_amdgcn_mfma_f32_32x32x16_bf16(a, bfr, acc[j], 0, 0, 0);
            }
        }
#pragma unroll
        for (int s = 0; s < 8; ++s) {
            short8 a = *(const short8*)(hc + s * 16);
#pragma unroll
            for (int j = 0; j < 2; ++j) {
                short8 bfr = *(const short8*)(wp + OFF_WE1 + (size_t)((s + 12) * 4 + cg * 2 + j) * 512 + lane * 8);
                acc[j] = __builtin_amdgcn_mfma_f32_32x32x16_bf16(a, bfr, acc[j], 0, 0, 0);
            }
        }
    }
    store32<2>(T1, acc, rg, colbase, r31, kh, true);    // Y1
    __syncthreads();   // B2: Y1 complete

    // ==== edge MLP layer 2 (K=128 spans both cg halves of Y1) ====
    gemm32_lds<8, 4, 2>(T1, wp + OFF_WE2, cg * 2, be2, acc, mrow, colbase, r31, kh, lane);
    __syncthreads();   // B2.5: all Y1 reads done before EF overwrites
    store32<2>(T1, acc, rg, colbase, r31, kh, true);    // EF
    __syncthreads();   // B3: EF complete

    // ==== coord MLP layer 1 (reads EF, all cols) ====
    gemm32_lds<8, 4, 2>(T1, wp + OFF_WC1, cg * 2, bc1, acc, mrow, colbase, r31, kh, lane);

    // ==== agg: segmented reduce over sorted rows (own rg rows, own cg cols) ====
    {
        const int col = colbase + lane;
        const int m0 = rg * 32;
        int curr = rows_s[m0];
        float s = 0.f;
        for (int m = m0; m < m0 + 32; ++m) {
            int r = rows_s[m];
            float vv = b2f(*(const unsigned short*)((const char*)T1 + m * 256 + (((col & 127) * 2) ^ ((m & 7) << 4))));
            if (r != curr) { atomicAdd(&agg[(size_t)curr * HD + (col & 127)], s); s = 0.f; curr = r; }
            s += vv;
        }
        atomicAdd(&agg[(size_t)curr * HD + (col & 127)], s);
    }
    __syncthreads();   // B4: EF reads (C1 gemm + reduce) done
    store32<2>(T1, acc, rg, colbase, r31, kh, true);    // C1
    __syncthreads();   // B5: C1 complete

    // ==== coord final layer (cg=0 waves; N=22 fits one 32-col frag) + wind ====
    if (cg == 0) {
        gemm32_lds<8, 1, 1>(T1, wp + OFF_WCL, 0, (const float*)nullptr, acc, mrow, 0, r31, kh, lane);
        float* O22 = (float*)Twd;               // 64x32 f32 overlay (wd dead)
#pragma unroll
        for (int reg = 0; reg < 16; ++reg) {
            int row = rg * 32 + (reg & 3) + 8 * (reg >> 2) + 4 * kh;
            O22[row * 32 + r31] = acc[0][reg];
        }
        // wind segmented reduce: 16-row chains (rg, kh) over own-wave rows
        const int c = r31;
        if (c < 22) {
            const bool isU = c < LVN;
            const int lvl = isU ? c : c - LVN;
            float* dst = isU ? aggu : aggv;
            const float* radp = isU ? radu_s : radv_s;
            const int m0 = rg * 32 + kh * 16;
            int curr = rows_s[m0]; float s = 0.f;
            for (int m = m0; m < m0 + 16; ++m) {
                int r = rows_s[m];
                float vv = O22[m * 32 + c] * radp[m];
                if (r != curr) { atomicAdd(&dst[(size_t)curr * LVN + lvl], s); s = 0.f; curr = r; }
                s += vv;
            }
            atomicAdd(&dst[(size_t)curr * LVN + lvl], s);
        }
    }
}

// ================= post: lat-band mean | wind finalize =================
__global__ __launch_bounds__(256)
void post_kernel(const float* __restrict__ agg, short* __restrict__ latb,
                 float* __restrict__ aggu, float* __restrict__ aggv,
                 const int* __restrict__ off)
{
    const int b = blockIdx.x, tid = threadIdx.x;
    if (b < NLAT) {
        __shared__ float part[256];
        const int j = tid & 127, half = tid >> 7;
        float s = 0.f;
        for (int lon = half * 120; lon < (half + 1) * 120; ++lon)
            s += agg[((size_t)b * NLON + lon) * HD + j];
        part[tid] = s;
        __syncthreads();
        if (tid < 128)
            latb[(size_t)b * HD + tid] = f2b((part[tid] + part[128 + tid]) * (1.0f / NLON));
        return;
    }
    int tt = (b - NLAT) * 256 + tid;
    if (tt >= NN * LVN) return;
    int n = tt / LVN;
    float c = fmaxf((float)(off[n + 1] - off[n]), 1.f);
    float xu = aggu[tt] / c, xv = aggv[tt] / c;
    aggu[tt] = fminf(fmaxf(xu, -100.f), 100.f);
    aggv[tt] = fminf(fmaxf(xv, -100.f), 100.f);
}

// ================= node kernel: 128-node tiles, 8 waves, 32x32x16 =================
__global__ __launch_bounds__(512, 4)
void node_mfma(const short* __restrict__ hb, const float* __restrict__ h,
               const short* __restrict__ latb,
               const float* __restrict__ bn1, const float* __restrict__ bn2,
               const short* __restrict__ wp, float* __restrict__ out)
{
    __shared__ short T1[128 * 128];    // 32 KB
    const int tid = threadIdx.x, lane = tid & 63, w = tid >> 6;   // 8 waves
    const int rg = w >> 1, cg = w & 1;                             // rg 0..3
    const int r31 = lane & 31, kh = lane >> 5;
    const int mrow = rg * 32 + r31;                                // 0..127
    const int sw = (mrow & 7) << 4;
    const int colbase = cg * 64;
    const int n0 = blockIdx.x * 128;
    const int n = n0 + mrow;
    const int nc = (n < NN) ? n : (NN - 1);
    const short* hp = hb + (size_t)nc * HD + 8 * kh;
    const float* ap = out + (size_t)nc * HD + 8 * kh;   // agg lives in out region
    const short* lp = latb + (size_t)(nc / NLON) * HD + 8 * kh;

    f16v acc[2];
#pragma unroll
    for (int j = 0; j < 2; ++j) {
        float bv = bn1[colbase + j * 32 + r31];
#pragma unroll
        for (int q = 0; q < 16; ++q) acc[j][q] = bv;
    }
    // h part (k 0..127)
#pragma unroll
    for (int s = 0; s < 8; ++s) {
        short8 a = *(const short8*)(hp + s * 16);
#pragma unroll
        for (int j = 0; j < 2; ++j) {
            short8 bfr = *(const short8*)(wp + OFF_WN1 + (size_t)(s * 4 + cg * 2 + j) * 512 + lane * 8);
            acc[j] = __builtin_amdgcn_mfma_f32_32x32x16_bf16(a, bfr, acc[j], 0, 0, 0);
        }
    }
    // agg part (k 128..255), f32 -> bf16 in reg
#pragma unroll
    for (int s = 0; s < 8; ++s) {
        short8 a;
#pragma unroll
        for (int q = 0; q < 8; ++q) a[q] = f2b(ap[s * 16 + q]);
#pragma unroll
        for (int j = 0; j < 2; ++j) {
            short8 bfr = *(const short8*)(wp + OFF_WN1 + (size_t)((s + 8) * 4 + cg * 2 + j) * 512 + lane * 8);
            acc[j] = __builtin_amdgcn_mfma_f32_32x32x16_bf16(a, bfr, acc[j], 0, 0, 0);
        }
    }
    // lat part (k 256..383)
#pragma unroll
    for (int s = 0; s < 8; ++s) {
        short8 a = *(const short8*)(lp + s * 16);
#pragma unroll
        for (int j = 0; j < 2; ++j) {
            short8 bfr = *(const short8*)(wp + OFF_WN1 + (size_t)((s + 16) * 4 + cg * 2 + j) * 512 + lane * 8);
            acc[j] = __builtin_amdgcn_mfma_f32_32x32x16_bf16(a, bfr, acc[j], 0, 0, 0);
        }
    }
    store32<2>(T1, acc, rg, colbase, r31, kh, true);
    __syncthreads();   // Wn2 K spans both cg halves
    gemm32_lds<8, 4, 2>(T1, wp + OFF_WN2, cg * 2, bn2, acc, mrow, colbase, r31, kh, lane);

    // out = acc + h (residual)
#pragma unroll
    for (int j = 0; j < 2; ++j)
#pragma unroll
        for (int reg = 0; reg < 16; ++reg) {
            int row = rg * 32 + (reg & 3) + 8 * (reg >> 2) + 4 * kh;
            int gn = n0 + row;
            if (gn < NN) {
                int col = colbase + j * 32 + r31;
                out[(size_t)gn * HD + col] = acc[j][reg] + h[(size_t)gn * HD + col];
            }
        }
}

extern "C" void kernel_launch(void* const* d_in, const int* in_sizes, int n_in,
                              void* d_out, int out_size, void* d_ws, size_t ws_size,
                              hipStream_t stream)
{
    const float* h   = (const float*)d_in[0];
    const float* u   = (const float*)d_in[1];
    const float* v   = (const float*)d_in[2];
    const float* ea  = (const float*)d_in[3];
    const float* We1 = (const float*)d_in[4];
    const float* be1 = (const float*)d_in[5];
    const float* We2 = (const float*)d_in[6];
    const float* be2 = (const float*)d_in[7];
    const float* Wn1 = (const float*)d_in[8];
    const float* bn1 = (const float*)d_in[9];
    const float* Wn2 = (const float*)d_in[10];
    const float* bn2 = (const float*)d_in[11];
    const float* Wc1 = (const float*)d_in[12];
    const float* bc1 = (const float*)d_in[13];
    const float* Wcl = (const float*)d_in[14];
    const int*   eidx = (const int*)d_in[15];

    float* out  = (float*)d_out;
    float* agg  = out;                       // [NN,HD]: agg accum, then h_out
    float* aggu = out + (size_t)NN * HD;
    float* aggv = aggu + (size_t)NN * LVN;

    // ---- workspace layout (no overlaps) ----
    char* p = (char*)d_ws;
    short* wp  = (short*)p;                  p += (size_t)WP_SHORTS * 2;
    int*   off = (int*)p;                    p += (size_t)(NN + 1) * 4;
    int*   csr = (int*)p;                    p += (size_t)EE * 4;
    p = (char*)(((size_t)p + 15) & ~(size_t)15);
    short* hb  = (short*)p;                  p += (size_t)NN * HD * 2;
    float* uvr = (float*)p;                  p += (size_t)NN * 36 * 4;
    short* latb = (short*)p;                 p += (size_t)NLAT * HD * 2;
    p = (char*)(((size_t)p + 15) & ~(size_t)15);
    int*   cnt = (int*)p;                    p += (size_t)NN * 4;
    int*   cur = (int*)p;

    hipMemsetAsync(d_out, 0, (size_t)out_size * sizeof(float), stream);
    hipMemsetAsync(cnt, 0, (size_t)2 * NN * sizeof(int), stream);

    setup_kernel<<<SB_HIST + SB_HCAST + SB_UV + SB_WP, 256, 0, stream>>>(
        eidx, cnt, h, hb, u, v, uvr, We1, We2, Wc1, Wcl, Wn1, Wn2, wp);
    scan_kernel<<<1, 1024, 0, stream>>>(cnt, off);
    scatter_kernel<<<EE / 256, 256, 0, stream>>>(eidx, off, cur, csr);

    edge_mfma<<<EE / 64, 256, 0, stream>>>(hb, uvr, ea, be1, be2, bc1,
                                           wp, eidx, csr, agg, aggu, aggv);

    post_kernel<<<NLAT + (NN * LVN + 255) / 256, 256, 0, stream>>>(
        agg, latb, aggu, aggv, off);

    node_mfma<<<(NN + 127) / 128, 512, 0, stream>>>(hb, h, latb, bn1, bn2, wp, agg);
}

// Round 13
// 294.015 us; speedup vs baseline: 1.1700x; 1.1700x over previous
//
#include <hip/hip_runtime.h>
#include <hip/hip_bf16.h>
#include <math.h>

#define NN   29040
#define NLAT 121
#define NLON 240
#define HD   128
#define LVN  11
#define EE   464640

typedef __attribute__((ext_vector_type(8))) short short8;
typedef __attribute__((ext_vector_type(16))) float f16v;

// packed-weight offsets (in shorts) inside wp buffer
#define OFF_WE1 0          // 20 kf x 4 nf  = 80 frags (1 KB each)
#define OFF_WE2 40960      // 8 x 4 = 32
#define OFF_WC1 57344      // 8 x 4 = 32
#define OFF_WCL 73728      // 8 x 1 = 8
#define OFF_WN1 77824      // 24 x 4 = 96
#define OFF_WN2 126976     // 8 x 4 = 32
#define WP_SHORTS 143360

__device__ inline short f2b(float x) {
    union { __hip_bfloat16 b; short s; } v;
    v.b = __float2bfloat16(x);
    return v.s;
}
__device__ inline float b2f(unsigned short b) {
    union { unsigned u; float f; } v; v.u = ((unsigned)b) << 16;
    return v.f;
}

// ================= fused setup: hist | h-cast | uv-prep | weight-pack =================
#define SB_HIST  1815
#define SB_HCAST 1815
#define SB_UV    114
#define SB_WP    70

__global__ __launch_bounds__(256)
void setup_kernel(const int* __restrict__ eidx, int* __restrict__ cnt,
                  const float* __restrict__ h, short* __restrict__ hb,
                  const float* __restrict__ u, const float* __restrict__ v,
                  short* __restrict__ uvb,
                  const float* __restrict__ We1, const float* __restrict__ We2,
                  const float* __restrict__ Wc1, const float* __restrict__ Wcl,
                  const float* __restrict__ Wn1, const float* __restrict__ Wn2,
                  short* __restrict__ wp)
{
    const int b = blockIdx.x, tid = threadIdx.x;
    if (b < SB_HIST) {
        int e = b * 256 + tid;
        atomicAdd(&cnt[eidx[e]], 1);
        return;
    }
    if (b < SB_HIST + SB_HCAST) {
        int idx = (b - SB_HIST) * 256 + tid;          // 8 elems each
        const float4* hf = (const float4*)h;
        float4 a = hf[idx * 2], c = hf[idx * 2 + 1];
        short8 o;
        o[0] = f2b(a.x); o[1] = f2b(a.y); o[2] = f2b(a.z); o[3] = f2b(a.w);
        o[4] = f2b(c.x); o[5] = f2b(c.y); o[6] = f2b(c.z); o[7] = f2b(c.w);
        ((short8*)hb)[idx] = o;
        return;
    }
    if (b < SB_HIST + SB_HCAST + SB_UV) {
        int n = (b - SB_HIST - SB_HCAST) * 256 + tid;
        if (n >= NN) return;
        // compact bf16 record, 40 shorts = 80B (vs 144B f32):
        // [0..10]=u/s  [11..21]=v/s  [22..32]=s  [33]=|u|  [34]=|v|  [35..39]=0
        short* r = uvb + (size_t)n * 40;
        float un = 0.f, vn = 0.f;
#pragma unroll
        for (int l = 0; l < LVN; ++l) {
            float uu = u[n * LVN + l], vv = v[n * LVN + l];
            float s = sqrtf(uu * uu + vv * vv);
            r[l]      = f2b(uu / s);
            r[11 + l] = f2b(vv / s);
            r[22 + l] = f2b(s);
            un += uu * uu; vn += vv * vv;
        }
        r[33] = f2b(sqrtf(un));
        r[34] = f2b(sqrtf(vn));
        r[35] = 0; r[36] = 0; r[37] = 0; r[38] = 0; r[39] = 0;
        return;
    }
    // ---- weight pack for 32x32x16 MFMA B-fragments ----
    // lane l, elem i -> k = kf*16 + 8*(l>>5) + i ; n = nf*32 + (l&31)
    {
        int fg = (b - SB_HIST - SB_HCAST - SB_UV) * 4 + (tid >> 6);   // 0..279
        const int l = tid & 63;
        int kind, f, base;
        if (fg < 80)       { kind = 0; f = fg;       base = OFF_WE1; }   // 20x4
        else if (fg < 112) { kind = 1; f = fg - 80;  base = OFF_WE2; }   // 8x4
        else if (fg < 144) { kind = 2; f = fg - 112; base = OFF_WC1; }   // 8x4
        else if (fg < 152) { kind = 3; f = fg - 144; base = OFF_WCL; }   // 8x1
        else if (fg < 248) { kind = 4; f = fg - 152; base = OFF_WN1; }   // 24x4
        else               { kind = 5; f = fg - 248; base = OFF_WN2; }   // 8x4
        const int nfw = (kind == 3) ? 1 : 4;
        const int kf = f / nfw, nf = f % nfw;
        short* dst = wp + base + (size_t)f * 512 + l * 8;
        for (int i = 0; i < 8; ++i) {
            int k = kf * 16 + ((l >> 5) << 3) + i;
            int n = nf * 32 + (l & 31);
            float val = 0.f;
            if (kind == 0) {
                int r = (k < 33) ? (256 + k) : (k == 33 ? 289 : (k < 64 ? -1 : k - 64));
                if (r >= 0) val = We1[r * HD + n];
            } else if (kind == 1) val = We2[k * HD + n];
            else if (kind == 2)  val = Wc1[k * HD + n];
            else if (kind == 3)  { if (n < 22) val = Wcl[k * 22 + n]; }
            else if (kind == 4)  val = Wn1[k * HD + n];
            else                 val = Wn2[k * HD + n];
            dst[i] = f2b(val);
        }
    }
}

// ================= CSR scan + scatter =================
__global__ __launch_bounds__(1024)
void scan_kernel(const int* __restrict__ cnt, int* __restrict__ off)
{
    __shared__ int part[1024];
    const int tid = threadIdx.x;
    const int CH = 29;
    int lo = tid * CH, hi = min(lo + CH, NN);
    int s = 0;
    for (int i = lo; i < hi; ++i) s += cnt[i];
    part[tid] = s;
    __syncthreads();
    for (int d = 1; d < 1024; d <<= 1) {
        int vv = (tid >= d) ? part[tid - d] : 0;
        __syncthreads();
        part[tid] += vv;
        __syncthreads();
    }
    int run = (tid == 0) ? 0 : part[tid - 1];
    for (int i = lo; i < hi; ++i) { off[i] = run; run += cnt[i]; }
    if (tid == 1023) off[NN] = run;
}

__global__ __launch_bounds__(256)
void scatter_kernel(const int* __restrict__ eidx, const int* __restrict__ off,
                    int* __restrict__ cur, int* __restrict__ csr)
{
    int e = blockIdx.x * 256 + threadIdx.x;
    if (e >= EE) return;
    int row = eidx[e];
    int p = atomicAdd(&cur[row], 1);
    csr[off[row] + p] = e;
}

// ================= 32x32x16 GEMM helpers =================
// A row = mrow (lane&31 within row-group), k = kf*16 + 8*(lane>>5) + i.
// C: col = lane&31, row = (reg&3) + 8*(reg>>2) + 4*(lane>>5)   [HW-verified m74/m101]
template<int KF, int NFL, int NJ>
__device__ inline void gemm32_lds(const short* At, const short* Wp, int nf0,
                                  const float* bias, f16v* acc,
                                  int mrow, int colbase, int r31, int kh, int lane)
{
    const char* arow = (const char*)At + mrow * 256;
    const int sw = (mrow & 7) << 4;
#pragma unroll
    for (int j = 0; j < NJ; ++j) {
        float bv = bias ? bias[colbase + j * 32 + r31] : 0.f;
#pragma unroll
        for (int q = 0; q < 16; ++q) acc[j][q] = bv;
    }
#pragma unroll
    for (int kf = 0; kf < KF; ++kf) {
        short8 a = *(const short8*)(arow + ((kf * 32 + 16 * kh) ^ sw));
#pragma unroll
        for (int j = 0; j < NJ; ++j) {
            short8 bfr = *(const short8*)(Wp + (size_t)(kf * NFL + nf0 + j) * 512 + lane * 8);
            acc[j] = __builtin_amdgcn_mfma_f32_32x32x16_bf16(a, bfr, acc[j], 0, 0, 0);
        }
    }
}

// store C (optionally relu) as bf16 row-major tile, 256B rows, XOR-swizzled
template<int NJ>
__device__ inline void store32(short* tile, const f16v* acc, int rg, int colbase,
                               int r31, int kh, bool relu)
{
#pragma unroll
    for (int j = 0; j < NJ; ++j)
#pragma unroll
        for (int reg = 0; reg < 16; ++reg) {
            int row = rg * 32 + (reg & 3) + 8 * (reg >> 2) + 4 * kh;
            int cb2 = (colbase + j * 32 + r31) * 2;
            float vv = acc[j][reg];
            if (relu) vv = fmaxf(vv, 0.f);
            *(short*)((char*)tile + row * 256 + (cb2 ^ ((row & 7) << 4))) = f2b(vv);
        }
}

// ================= edge kernel: 64-edge tiles, 32x32x16 MFMA =================
// (256,4) — r10's proven config. r12 measured that raising the occupancy floor
// to 5 waves/EU cut VGPR to 48 and raised FETCH 186->284 MB (L2 thrash from
// more concurrent random gathers): occupancy and cache hit rate trade off, and
// 4 waves/SIMD x 64 VGPR is the sweet spot. This round instead cuts the
// col-side random-gather bytes (uvrec f32->bf16: 400->336 B/edge).
__global__ __launch_bounds__(256, 4)
void edge_mfma(const short* __restrict__ hb, const short* __restrict__ uvb,
               const float* __restrict__ ea,
               const float* __restrict__ be1, const float* __restrict__ be2,
               const float* __restrict__ bc1,
               const short* __restrict__ wp,
               const int* __restrict__ eidx, const int* __restrict__ csr,
               float* __restrict__ agg, float* __restrict__ aggu,
               float* __restrict__ aggv)
{
    __shared__ short Twd[64 * 64];     // 8 KB wd tile (128B rows); later O22 f32 overlay
    __shared__ short T1[64 * 128];     // 16 KB tile (256B rows)
    __shared__ int   rows_s[64];
    __shared__ float radu_s[64], radv_s[64];

    const int tid = threadIdx.x, lane = tid & 63, w = tid >> 6;
    const int rg = w >> 1, cg = w & 1;
    const int e0 = blockIdx.x * 64;
    const int r31 = lane & 31, kh = lane >> 5;
    const int mrow = rg * 32 + r31;
    const int sw = (mrow & 7) << 4;
    const int colbase = cg * 64;

    // own-row gather pointers (early issue; csr->eidx chain overlaps wd build)
    int e1 = csr[e0 + mrow];
    int rowm = eidx[e1], colm = eidx[EE + e1];
    const short* hr = hb + (size_t)rowm * HD + 8 * kh;
    const short* hc = hb + (size_t)colm * HD + 8 * kh;

    // ---- wd tile build (block-wide, 4 threads per row); uvb is bf16 ----
    {
        const int m2 = tid >> 2, q = tid & 3;
        const int sw2 = (m2 & 7) << 4;
        int e2 = csr[e0 + m2];
        int row2 = eidx[e2], col2 = eidx[EE + e2];
        const short* rc = uvb + (size_t)col2 * 40;
        const short* rr = uvb + (size_t)row2 * 40;
        char* arow = (char*)(Twd + m2 * 64);
        short8 z = {0, 0, 0, 0, 0, 0, 0, 0};
        *(short8*)(arow + q * 32) = z;
        *(short8*)(arow + q * 32 + 16) = z;
        for (int l = q; l < LVN; l += 4) {
            float rel = b2f((unsigned short)rc[l]) * b2f((unsigned short)rr[l])
                      + b2f((unsigned short)rc[11 + l]) * b2f((unsigned short)rr[11 + l]);
            *(short*)(arow + ((2 * l) ^ sw2))        = f2b(rel);
            *(short*)(arow + ((2 * (11 + l)) ^ sw2)) = rc[22 + l];   // already bf16
            *(short*)(arow + ((2 * (22 + l)) ^ sw2)) = rr[22 + l];
        }
        if (q == 0) {
            rows_s[m2] = row2;
            radu_s[m2] = b2f((unsigned short)rc[33]);
            radv_s[m2] = b2f((unsigned short)rc[34]);
        }
        if (q == 3) *(short*)(arow + ((2 * 33) ^ sw2)) = f2b(ea[e2]);
    }
    __syncthreads();   // B1: Twd/rows_s/rad visible

    // ==== edge MLP layer 1: A = [wd(k 0..63) | h_row(64..191) | h_col(192..319)] ====
    f16v acc[2];
#pragma unroll
    for (int j = 0; j < 2; ++j) {
        float bv = be1[colbase + j * 32 + r31];
#pragma unroll
        for (int q = 0; q < 16; ++q) acc[j][q] = bv;
    }
    {
        const char* awd = (const char*)(Twd + mrow * 64);
#pragma unroll
        for (int kf = 0; kf < 4; ++kf) {
            short8 a = *(const short8*)(awd + ((kf * 32 + 16 * kh) ^ sw));
#pragma unroll
            for (int j = 0; j < 2; ++j) {
                short8 bfr = *(const short8*)(wp + OFF_WE1 + (size_t)(kf * 4 + cg * 2 + j) * 512 + lane * 8);
                acc[j] = __builtin_amdgcn_mfma_f32_32x32x16_bf16(a, bfr, acc[j], 0, 0, 0);
            }
        }
#pragma unroll
        for (int s = 0; s < 8; ++s) {
            short8 a = *(const short8*)(hr + s * 16);
#pragma unroll
            for (int j = 0; j < 2; ++j) {
                short8 bfr = *(const short8*)(wp + OFF_WE1 + (size_t)((s + 4) * 4 + cg * 2 + j) * 512 + lane * 8);
                acc[j] = __builtin_amdgcn_mfma_f32_32x32x16_bf16(a, bfr, acc[j], 0, 0, 0);
            }
        }
#pragma unroll
        for (int s = 0; s < 8; ++s) {
            short8 a = *(const short8*)(hc + s * 16);
#pragma unroll
            for (int j = 0; j < 2; ++j) {
                short8 bfr = *(const short8*)(wp + OFF_WE1 + (size_t)((s + 12) * 4 + cg * 2 + j) * 512 + lane * 8);
                acc[j] = __builtin_amdgcn_mfma_f32_32x32x16_bf16(a, bfr, acc[j], 0, 0, 0);
            }
        }
    }
    store32<2>(T1, acc, rg, colbase, r31, kh, true);    // Y1
    __syncthreads();   // B2: Y1 complete

    // ==== edge MLP layer 2 (K=128 spans both cg halves of Y1) ====
    gemm32_lds<8, 4, 2>(T1, wp + OFF_WE2, cg * 2, be2, acc, mrow, colbase, r31, kh, lane);
    __syncthreads();   // B2.5: all Y1 reads done before EF overwrites
    store32<2>(T1, acc, rg, colbase, r31, kh, true);    // EF
    __syncthreads();   // B3: EF complete

    // ==== coord MLP layer 1 (reads EF, all cols) ====
    gemm32_lds<8, 4, 2>(T1, wp + OFF_WC1, cg * 2, bc1, acc, mrow, colbase, r31, kh, lane);

    // ==== agg: segmented reduce over sorted rows (own rg rows, own cg cols) ====
    {
        const int col = colbase + lane;
        const int m0 = rg * 32;
        int curr = rows_s[m0];
        float s = 0.f;
        for (int m = m0; m < m0 + 32; ++m) {
            int r = rows_s[m];
            float vv = b2f(*(const unsigned short*)((const char*)T1 + m * 256 + (((col & 127) * 2) ^ ((m & 7) << 4))));
            if (r != curr) { atomicAdd(&agg[(size_t)curr * HD + (col & 127)], s); s = 0.f; curr = r; }
            s += vv;
        }
        atomicAdd(&agg[(size_t)curr * HD + (col & 127)], s);
    }
    __syncthreads();   // B4: EF reads (C1 gemm + reduce) done
    store32<2>(T1, acc, rg, colbase, r31, kh, true);    // C1
    __syncthreads();   // B5: C1 complete

    // ==== coord final layer (cg=0 waves; N=22 fits one 32-col frag) + wind ====
    if (cg == 0) {
        gemm32_lds<8, 1, 1>(T1, wp + OFF_WCL, 0, (const float*)nullptr, acc, mrow, 0, r31, kh, lane);
        float* O22 = (float*)Twd;               // 64x32 f32 overlay (wd dead)
#pragma unroll
        for (int reg = 0; reg < 16; ++reg) {
            int row = rg * 32 + (reg & 3) + 8 * (reg >> 2) + 4 * kh;
            O22[row * 32 + r31] = acc[0][reg];
        }
        // wind segmented reduce: 16-row chains (rg, kh) over own-wave rows
        const int c = r31;
        if (c < 22) {
            const bool isU = c < LVN;
            const int lvl = isU ? c : c - LVN;
            float* dst = isU ? aggu : aggv;
            const float* radp = isU ? radu_s : radv_s;
            const int m0 = rg * 32 + kh * 16;
            int curr = rows_s[m0]; float s = 0.f;
            for (int m = m0; m < m0 + 16; ++m) {
                int r = rows_s[m];
                float vv = O22[m * 32 + c] * radp[m];
                if (r != curr) { atomicAdd(&dst[(size_t)curr * LVN + lvl], s); s = 0.f; curr = r; }
                s += vv;
            }
            atomicAdd(&dst[(size_t)curr * LVN + lvl], s);
        }
    }
}

// ================= post: lat-band mean only =================
__global__ __launch_bounds__(256)
void post_kernel(const float* __restrict__ agg, short* __restrict__ latb)
{
    const int b = blockIdx.x, tid = threadIdx.x;
    __shared__ float part[256];
    const int j = tid & 127, half = tid >> 7;
    float s = 0.f;
    for (int lon = half * 120; lon < (half + 1) * 120; ++lon)
        s += agg[((size_t)b * NLON + lon) * HD + j];
    part[tid] = s;
    __syncthreads();
    if (tid < 128)
        latb[(size_t)b * HD + tid] = f2b((part[tid] + part[128 + tid]) * (1.0f / NLON));
}

// ================= node kernel: 128-node tiles, 8 waves, 32x32x16 + wind finalize =================
__global__ __launch_bounds__(512, 4)
void node_mfma(const short* __restrict__ hb, const float* __restrict__ h,
               const short* __restrict__ latb,
               const float* __restrict__ bn1, const float* __restrict__ bn2,
               const short* __restrict__ wp, float* __restrict__ out,
               float* __restrict__ aggu, float* __restrict__ aggv,
               const int* __restrict__ off)
{
    __shared__ short T1[128 * 128];    // 32 KB
    const int tid = threadIdx.x, lane = tid & 63, w = tid >> 6;   // 8 waves
    const int rg = w >> 1, cg = w & 1;                             // rg 0..3
    const int r31 = lane & 31, kh = lane >> 5;
    const int mrow = rg * 32 + r31;                                // 0..127
    const int sw = (mrow & 7) << 4;
    const int colbase = cg * 64;
    const int n0 = blockIdx.x * 128;
    const int n = n0 + mrow;
    const int nc = (n < NN) ? n : (NN - 1);
    const short* hp = hb + (size_t)nc * HD + 8 * kh;
    const float* ap = out + (size_t)nc * HD + 8 * kh;   // agg lives in out region
    const short* lp = latb + (size_t)(nc / NLON) * HD + 8 * kh;

    f16v acc[2];
#pragma unroll
    for (int j = 0; j < 2; ++j) {
        float bv = bn1[colbase + j * 32 + r31];
#pragma unroll
        for (int q = 0; q < 16; ++q) acc[j][q] = bv;
    }
    // h part (k 0..127)
#pragma unroll
    for (int s = 0; s < 8; ++s) {
        short8 a = *(const short8*)(hp + s * 16);
#pragma unroll
        for (int j = 0; j < 2; ++j) {
            short8 bfr = *(const short8*)(wp + OFF_WN1 + (size_t)(s * 4 + cg * 2 + j) * 512 + lane * 8);
            acc[j] = __builtin_amdgcn_mfma_f32_32x32x16_bf16(a, bfr, acc[j], 0, 0, 0);
        }
    }
    // agg part (k 128..255), f32 -> bf16 in reg
#pragma unroll
    for (int s = 0; s < 8; ++s) {
        short8 a;
#pragma unroll
        for (int q = 0; q < 8; ++q) a[q] = f2b(ap[s * 16 + q]);
#pragma unroll
        for (int j = 0; j < 2; ++j) {
            short8 bfr = *(const short8*)(wp + OFF_WN1 + (size_t)((s + 8) * 4 + cg * 2 + j) * 512 + lane * 8);
            acc[j] = __builtin_amdgcn_mfma_f32_32x32x16_bf16(a, bfr, acc[j], 0, 0, 0);
        }
    }
    // lat part (k 256..383)
#pragma unroll
    for (int s = 0; s < 8; ++s) {
        short8 a = *(const short8*)(lp + s * 16);
#pragma unroll
        for (int j = 0; j < 2; ++j) {
            short8 bfr = *(const short8*)(wp + OFF_WN1 + (size_t)((s + 16) * 4 + cg * 2 + j) * 512 + lane * 8);
            acc[j] = __builtin_amdgcn_mfma_f32_32x32x16_bf16(a, bfr, acc[j], 0, 0, 0);
        }
    }
    store32<2>(T1, acc, rg, colbase, r31, kh, true);
    __syncthreads();   // Wn2 K spans both cg halves
    gemm32_lds<8, 4, 2>(T1, wp + OFF_WN2, cg * 2, bn2, acc, mrow, colbase, r31, kh, lane);

    // out = acc + h (residual)
#pragma unroll
    for (int j = 0; j < 2; ++j)
#pragma unroll
        for (int reg = 0; reg < 16; ++reg) {
            int row = rg * 32 + (reg & 3) + 8 * (reg >> 2) + 4 * kh;
            int gn = n0 + row;
            if (gn < NN) {
                int col = colbase + j * 32 + r31;
                out[(size_t)gn * HD + col] = acc[j][reg] + h[(size_t)gn * HD + col];
            }
        }

    // ---- fused wind finalize (grid-stride; independent of the GEMM above) ----
    for (int tt = blockIdx.x * 512 + tid; tt < NN * LVN; tt += gridDim.x * 512) {
        int nn2 = tt / LVN;
        float c = fmaxf((float)(off[nn2 + 1] - off[nn2]), 1.f);
        float xu = aggu[tt] / c, xv = aggv[tt] / c;
        aggu[tt] = fminf(fmaxf(xu, -100.f), 100.f);
        aggv[tt] = fminf(fmaxf(xv, -100.f), 100.f);
    }
}

extern "C" void kernel_launch(void* const* d_in, const int* in_sizes, int n_in,
                              void* d_out, int out_size, void* d_ws, size_t ws_size,
                              hipStream_t stream)
{
    const float* h   = (const float*)d_in[0];
    const float* u   = (const float*)d_in[1];
    const float* v   = (const float*)d_in[2];
    const float* ea  = (const float*)d_in[3];
    const float* We1 = (const float*)d_in[4];
    const float* be1 = (const float*)d_in[5];
    const float* We2 = (const float*)d_in[6];
    const float* be2 = (const float*)d_in[7];
    const float* Wn1 = (const float*)d_in[8];
    const float* bn1 = (const float*)d_in[9];
    const float* Wn2 = (const float*)d_in[10];
    const float* bn2 = (const float*)d_in[11];
    const float* Wc1 = (const float*)d_in[12];
    const float* bc1 = (const float*)d_in[13];
    const float* Wcl = (const float*)d_in[14];
    const int*   eidx = (const int*)d_in[15];

    float* out  = (float*)d_out;
    float* agg  = out;                       // [NN,HD]: agg accum, then h_out
    float* aggu = out + (size_t)NN * HD;
    float* aggv = aggu + (size_t)NN * LVN;

    // ---- workspace layout (no overlaps) ----
    char* p = (char*)d_ws;
    short* wp  = (short*)p;                  p += (size_t)WP_SHORTS * 2;
    int*   off = (int*)p;                    p += (size_t)(NN + 1) * 4;
    int*   csr = (int*)p;                    p += (size_t)EE * 4;
    p = (char*)(((size_t)p + 15) & ~(size_t)15);
    short* hb  = (short*)p;                  p += (size_t)NN * HD * 2;
    short* uvb = (short*)p;                  p += (size_t)NN * 40 * 2;
    short* latb = (short*)p;                 p += (size_t)NLAT * HD * 2;
    p = (char*)(((size_t)p + 15) & ~(size_t)15);
    int*   cnt = (int*)p;                    p += (size_t)NN * 4;
    int*   cur = (int*)p;

    hipMemsetAsync(d_out, 0, (size_t)out_size * sizeof(float), stream);
    hipMemsetAsync(cnt, 0, (size_t)2 * NN * sizeof(int), stream);

    setup_kernel<<<SB_HIST + SB_HCAST + SB_UV + SB_WP, 256, 0, stream>>>(
        eidx, cnt, h, hb, u, v, uvb, We1, We2, Wc1, Wcl, Wn1, Wn2, wp);
    scan_kernel<<<1, 1024, 0, stream>>>(cnt, off);
    scatter_kernel<<<EE / 256, 256, 0, stream>>>(eidx, off, cur, csr);

    edge_mfma<<<EE / 64, 256, 0, stream>>>(hb, uvb, ea, be1, be2, bc1,
                                           wp, eidx, csr, agg, aggu, aggv);

    post_kernel<<<NLAT, 256, 0, stream>>>(agg, latb);

    node_mfma<<<(NN + 127) / 128, 512, 0, stream>>>(hb, h, latb, bn1, bn2, wp,
                                                    agg, aggu, aggv, off);
}

// Round 14
// 287.074 us; speedup vs baseline: 1.1983x; 1.0242x over previous
//
#include <hip/hip_runtime.h>
#include <hip/hip_bf16.h>
#include <math.h>

#define NN   29040
#define NLAT 121
#define NLON 240
#define HD   128
#define LVN  11
#define EE   464640

typedef __attribute__((ext_vector_type(8))) short short8;
typedef __attribute__((ext_vector_type(16))) float f16v;

// packed-weight offsets (in shorts) inside wp buffer
#define OFF_WE1 0          // 20 kf x 4 nf  = 80 frags (1 KB each)
#define OFF_WE2 40960      // 8 x 4 = 32
#define OFF_WC1 57344      // 8 x 4 = 32
#define OFF_WCL 73728      // 8 x 1 = 8
#define OFF_WN1 77824      // 24 x 4 = 96
#define OFF_WN2 126976     // 8 x 4 = 32
#define WP_SHORTS 143360

__device__ inline short f2b(float x) {
    union { __hip_bfloat16 b; short s; } v;
    v.b = __float2bfloat16(x);
    return v.s;
}
__device__ inline float b2f(unsigned short b) {
    union { unsigned u; float f; } v; v.u = ((unsigned)b) << 16;
    return v.f;
}

// ================= fused setup: hist | h-cast | uv-prep | weight-pack =================
#define SB_HIST  1815
#define SB_HCAST 1815
#define SB_UV    114
#define SB_WP    70

__global__ __launch_bounds__(256)
void setup_kernel(const int* __restrict__ eidx, int* __restrict__ cnt,
                  const float* __restrict__ h, short* __restrict__ hb,
                  const float* __restrict__ u, const float* __restrict__ v,
                  short* __restrict__ uvb,
                  const float* __restrict__ We1, const float* __restrict__ We2,
                  const float* __restrict__ Wc1, const float* __restrict__ Wcl,
                  const float* __restrict__ Wn1, const float* __restrict__ Wn2,
                  short* __restrict__ wp)
{
    const int b = blockIdx.x, tid = threadIdx.x;
    if (b < SB_HIST) {
        int e = b * 256 + tid;
        atomicAdd(&cnt[eidx[e]], 1);
        return;
    }
    if (b < SB_HIST + SB_HCAST) {
        int idx = (b - SB_HIST) * 256 + tid;          // 8 elems each
        const float4* hf = (const float4*)h;
        float4 a = hf[idx * 2], c = hf[idx * 2 + 1];
        short8 o;
        o[0] = f2b(a.x); o[1] = f2b(a.y); o[2] = f2b(a.z); o[3] = f2b(a.w);
        o[4] = f2b(c.x); o[5] = f2b(c.y); o[6] = f2b(c.z); o[7] = f2b(c.w);
        ((short8*)hb)[idx] = o;
        return;
    }
    if (b < SB_HIST + SB_HCAST + SB_UV) {
        int n = (b - SB_HIST - SB_HCAST) * 256 + tid;
        if (n >= NN) return;
        // compact bf16 record, 40 shorts = 80B:
        // [0..10]=u/s  [11..21]=v/s  [22..32]=s  [33]=|u|  [34]=|v|  [35..39]=0
        short* r = uvb + (size_t)n * 40;
        float un = 0.f, vn = 0.f;
#pragma unroll
        for (int l = 0; l < LVN; ++l) {
            float uu = u[n * LVN + l], vv = v[n * LVN + l];
            float s = sqrtf(uu * uu + vv * vv);
            r[l]      = f2b(uu / s);
            r[11 + l] = f2b(vv / s);
            r[22 + l] = f2b(s);
            un += uu * uu; vn += vv * vv;
        }
        r[33] = f2b(sqrtf(un));
        r[34] = f2b(sqrtf(vn));
        r[35] = 0; r[36] = 0; r[37] = 0; r[38] = 0; r[39] = 0;
        return;
    }
    // ---- weight pack for 32x32x16 MFMA B-fragments ----
    // lane l, elem i -> k = kf*16 + 8*(l>>5) + i ; n = nf*32 + (l&31)
    {
        int fg = (b - SB_HIST - SB_HCAST - SB_UV) * 4 + (tid >> 6);   // 0..279
        const int l = tid & 63;
        int kind, f, base;
        if (fg < 80)       { kind = 0; f = fg;       base = OFF_WE1; }   // 20x4
        else if (fg < 112) { kind = 1; f = fg - 80;  base = OFF_WE2; }   // 8x4
        else if (fg < 144) { kind = 2; f = fg - 112; base = OFF_WC1; }   // 8x4
        else if (fg < 152) { kind = 3; f = fg - 144; base = OFF_WCL; }   // 8x1
        else if (fg < 248) { kind = 4; f = fg - 152; base = OFF_WN1; }   // 24x4
        else               { kind = 5; f = fg - 248; base = OFF_WN2; }   // 8x4
        const int nfw = (kind == 3) ? 1 : 4;
        const int kf = f / nfw, nf = f % nfw;
        short* dst = wp + base + (size_t)f * 512 + l * 8;
        for (int i = 0; i < 8; ++i) {
            int k = kf * 16 + ((l >> 5) << 3) + i;
            int n = nf * 32 + (l & 31);
            float val = 0.f;
            if (kind == 0) {
                int r = (k < 33) ? (256 + k) : (k == 33 ? 289 : (k < 64 ? -1 : k - 64));
                if (r >= 0) val = We1[r * HD + n];
            } else if (kind == 1) val = We2[k * HD + n];
            else if (kind == 2)  val = Wc1[k * HD + n];
            else if (kind == 3)  { if (n < 22) val = Wcl[k * 22 + n]; }
            else if (kind == 4)  val = Wn1[k * HD + n];
            else                 val = Wn2[k * HD + n];
            dst[i] = f2b(val);
        }
    }
}

// ================= CSR scan + reordering scatter =================
__global__ __launch_bounds__(1024)
void scan_kernel(const int* __restrict__ cnt, int* __restrict__ off)
{
    __shared__ int part[1024];
    const int tid = threadIdx.x;
    const int CH = 29;
    int lo = tid * CH, hi = min(lo + CH, NN);
    int s = 0;
    for (int i = lo; i < hi; ++i) s += cnt[i];
    part[tid] = s;
    __syncthreads();
    for (int d = 1; d < 1024; d <<= 1) {
        int vv = (tid >= d) ? part[tid - d] : 0;
        __syncthreads();
        part[tid] += vv;
        __syncthreads();
    }
    int run = (tid == 0) ? 0 : part[tid - 1];
    for (int i = lo; i < hi; ++i) { off[i] = run; run += cnt[i]; }
    if (tid == 1023) off[NN] = run;
}

// writes the edge payload (row, col, ea) in CSR order. The random writes are
// fire-and-forget here; the edge kernel then reads everything COALESCED —
// removing two random-read latency hops (csr->eidx) from every edge-kernel
// phase (the r13-diagnosed residual stall).
__global__ __launch_bounds__(256)
void scatter_kernel(const int* __restrict__ eidx, const float* __restrict__ ea,
                    const int* __restrict__ off, int* __restrict__ cur,
                    int* __restrict__ rows_r, int* __restrict__ cols_r,
                    float* __restrict__ ear)
{
    int e = blockIdx.x * 256 + threadIdx.x;
    if (e >= EE) return;
    int row = eidx[e];
    int col = eidx[EE + e];
    float a = ea[e];
    int p = atomicAdd(&cur[row], 1);
    int idx = off[row] + p;
    rows_r[idx] = row;
    cols_r[idx] = col;
    ear[idx] = a;
}

// ================= 32x32x16 GEMM helpers =================
// A row = mrow, k = kf*16 + 8*(lane>>5) + i.
// C: col = lane&31, row = (reg&3) + 8*(reg>>2) + 4*(lane>>5)   [HW-verified m74/m101]
template<int KF, int NFL, int NJ>
__device__ inline void gemm32_lds(const short* At, const short* Wp, int nf0,
                                  const float* bias, f16v* acc,
                                  int mrow, int colbase, int r31, int kh, int lane)
{
    const char* arow = (const char*)At + mrow * 256;
    const int sw = (mrow & 7) << 4;
#pragma unroll
    for (int j = 0; j < NJ; ++j) {
        float bv = bias ? bias[colbase + j * 32 + r31] : 0.f;
#pragma unroll
        for (int q = 0; q < 16; ++q) acc[j][q] = bv;
    }
#pragma unroll
    for (int kf = 0; kf < KF; ++kf) {
        short8 a = *(const short8*)(arow + ((kf * 32 + 16 * kh) ^ sw));
#pragma unroll
        for (int j = 0; j < NJ; ++j) {
            short8 bfr = *(const short8*)(Wp + (size_t)(kf * NFL + nf0 + j) * 512 + lane * 8);
            acc[j] = __builtin_amdgcn_mfma_f32_32x32x16_bf16(a, bfr, acc[j], 0, 0, 0);
        }
    }
}

// store C (optionally relu) as bf16 row-major tile, 256B rows, XOR-swizzled
template<int NJ>
__device__ inline void store32(short* tile, const f16v* acc, int rg, int colbase,
                               int r31, int kh, bool relu)
{
#pragma unroll
    for (int j = 0; j < NJ; ++j)
#pragma unroll
        for (int reg = 0; reg < 16; ++reg) {
            int row = rg * 32 + (reg & 3) + 8 * (reg >> 2) + 4 * kh;
            int cb2 = (colbase + j * 32 + r31) * 2;
            float vv = acc[j][reg];
            if (relu) vv = fmaxf(vv, 0.f);
            *(short*)((char*)tile + row * 256 + (cb2 ^ ((row & 7) << 4))) = f2b(vv);
        }
}

// ================= edge kernel: 64-edge tiles, 32x32x16 MFMA =================
// (256,4) — the r10/r12-measured sweet spot (4 waves/SIMD x 64 VGPR; more
// occupancy thrashes L2, fewer waves under-hides latency). Index/ea loads are
// now coalesced CSR-ordered streams; only the hb/uvb gathers remain random.
__global__ __launch_bounds__(256, 4)
void edge_mfma(const short* __restrict__ hb, const short* __restrict__ uvb,
               const int* __restrict__ rows_r, const int* __restrict__ cols_r,
               const float* __restrict__ ear,
               const float* __restrict__ be1, const float* __restrict__ be2,
               const float* __restrict__ bc1,
               const short* __restrict__ wp,
               float* __restrict__ agg, float* __restrict__ aggu,
               float* __restrict__ aggv)
{
    __shared__ short Twd[64 * 64];     // 8 KB wd tile (128B rows); later O22 f32 overlay
    __shared__ short T1[64 * 128];     // 16 KB tile (256B rows)
    __shared__ int   rows_s[64];
    __shared__ float radu_s[64], radv_s[64];

    const int tid = threadIdx.x, lane = tid & 63, w = tid >> 6;
    const int rg = w >> 1, cg = w & 1;
    const int e0 = blockIdx.x * 64;
    const int r31 = lane & 31, kh = lane >> 5;
    const int mrow = rg * 32 + r31;
    const int sw = (mrow & 7) << 4;
    const int colbase = cg * 64;

    // own-row gather pointers — index loads are COALESCED now
    int rowm = rows_r[e0 + mrow], colm = cols_r[e0 + mrow];
    const short* hr = hb + (size_t)rowm * HD + 8 * kh;
    const short* hc = hb + (size_t)colm * HD + 8 * kh;

    // ---- wd tile build (block-wide, 4 threads per row); uvb is bf16 ----
    {
        const int m2 = tid >> 2, q = tid & 3;
        const int sw2 = (m2 & 7) << 4;
        int row2 = rows_r[e0 + m2], col2 = cols_r[e0 + m2];
        const short* rc = uvb + (size_t)col2 * 40;
        const short* rr = uvb + (size_t)row2 * 40;
        char* arow = (char*)(Twd + m2 * 64);
        short8 z = {0, 0, 0, 0, 0, 0, 0, 0};
        *(short8*)(arow + q * 32) = z;
        *(short8*)(arow + q * 32 + 16) = z;
        for (int l = q; l < LVN; l += 4) {
            float rel = b2f((unsigned short)rc[l]) * b2f((unsigned short)rr[l])
                      + b2f((unsigned short)rc[11 + l]) * b2f((unsigned short)rr[11 + l]);
            *(short*)(arow + ((2 * l) ^ sw2))        = f2b(rel);
            *(short*)(arow + ((2 * (11 + l)) ^ sw2)) = rc[22 + l];   // already bf16
            *(short*)(arow + ((2 * (22 + l)) ^ sw2)) = rr[22 + l];
        }
        if (q == 0) {
            rows_s[m2] = row2;
            radu_s[m2] = b2f((unsigned short)rc[33]);
            radv_s[m2] = b2f((unsigned short)rc[34]);
        }
        if (q == 3) *(short*)(arow + ((2 * 33) ^ sw2)) = f2b(ear[e0 + m2]);
    }
    __syncthreads();   // B1: Twd/rows_s/rad visible

    // ==== edge MLP layer 1: A = [wd(k 0..63) | h_row(64..191) | h_col(192..319)] ====
    f16v acc[2];
#pragma unroll
    for (int j = 0; j < 2; ++j) {
        float bv = be1[colbase + j * 32 + r31];
#pragma unroll
        for (int q = 0; q < 16; ++q) acc[j][q] = bv;
    }
    {
        const char* awd = (const char*)(Twd + mrow * 64);
#pragma unroll
        for (int kf = 0; kf < 4; ++kf) {
            short8 a = *(const short8*)(awd + ((kf * 32 + 16 * kh) ^ sw));
#pragma unroll
            for (int j = 0; j < 2; ++j) {
                short8 bfr = *(const short8*)(wp + OFF_WE1 + (size_t)(kf * 4 + cg * 2 + j) * 512 + lane * 8);
                acc[j] = __builtin_amdgcn_mfma_f32_32x32x16_bf16(a, bfr, acc[j], 0, 0, 0);
            }
        }
#pragma unroll
        for (int s = 0; s < 8; ++s) {
            short8 a = *(const short8*)(hr + s * 16);
#pragma unroll
            for (int j = 0; j < 2; ++j) {
                short8 bfr = *(const short8*)(wp + OFF_WE1 + (size_t)((s + 4) * 4 + cg * 2 + j) * 512 + lane * 8);
                acc[j] = __builtin_amdgcn_mfma_f32_32x32x16_bf16(a, bfr, acc[j], 0, 0, 0);
            }
        }
#pragma unroll
        for (int s = 0; s < 8; ++s) {
            short8 a = *(const short8*)(hc + s * 16);
#pragma unroll
            for (int j = 0; j < 2; ++j) {
                short8 bfr = *(const short8*)(wp + OFF_WE1 + (size_t)((s + 12) * 4 + cg * 2 + j) * 512 + lane * 8);
                acc[j] = __builtin_amdgcn_mfma_f32_32x32x16_bf16(a, bfr, acc[j], 0, 0, 0);
            }
        }
    }
    store32<2>(T1, acc, rg, colbase, r31, kh, true);    // Y1
    __syncthreads();   // B2: Y1 complete

    // ==== edge MLP layer 2 (K=128 spans both cg halves of Y1) ====
    gemm32_lds<8, 4, 2>(T1, wp + OFF_WE2, cg * 2, be2, acc, mrow, colbase, r31, kh, lane);
    __syncthreads();   // B2.5: all Y1 reads done before EF overwrites
    store32<2>(T1, acc, rg, colbase, r31, kh, true);    // EF
    __syncthreads();   // B3: EF complete

    // ==== coord MLP layer 1 (reads EF, all cols) ====
    gemm32_lds<8, 4, 2>(T1, wp + OFF_WC1, cg * 2, bc1, acc, mrow, colbase, r31, kh, lane);

    // ==== agg: segmented reduce over sorted rows (own rg rows, own cg cols) ====
    {
        const int col = colbase + lane;
        const int m0 = rg * 32;
        int curr = rows_s[m0];
        float s = 0.f;
        for (int m = m0; m < m0 + 32; ++m) {
            int r = rows_s[m];
            float vv = b2f(*(const unsigned short*)((const char*)T1 + m * 256 + (((col & 127) * 2) ^ ((m & 7) << 4))));
            if (r != curr) { atomicAdd(&agg[(size_t)curr * HD + (col & 127)], s); s = 0.f; curr = r; }
            s += vv;
        }
        atomicAdd(&agg[(size_t)curr * HD + (col & 127)], s);
    }
    __syncthreads();   // B4: EF reads (C1 gemm + reduce) done
    store32<2>(T1, acc, rg, colbase, r31, kh, true);    // C1
    __syncthreads();   // B5: C1 complete

    // ==== coord final layer (cg=0 waves; N=22 fits one 32-col frag) + wind ====
    if (cg == 0) {
        gemm32_lds<8, 1, 1>(T1, wp + OFF_WCL, 0, (const float*)nullptr, acc, mrow, 0, r31, kh, lane);
        float* O22 = (float*)Twd;               // 64x32 f32 overlay (wd dead)
#pragma unroll
        for (int reg = 0; reg < 16; ++reg) {
            int row = rg * 32 + (reg & 3) + 8 * (reg >> 2) + 4 * kh;
            O22[row * 32 + r31] = acc[0][reg];
        }
        // wind segmented reduce: 16-row chains (rg, kh) over own-wave rows
        const int c = r31;
        if (c < 22) {
            const bool isU = c < LVN;
            const int lvl = isU ? c : c - LVN;
            float* dst = isU ? aggu : aggv;
            const float* radp = isU ? radu_s : radv_s;
            const int m0 = rg * 32 + kh * 16;
            int curr = rows_s[m0]; float s = 0.f;
            for (int m = m0; m < m0 + 16; ++m) {
                int r = rows_s[m];
                float vv = O22[m * 32 + c] * radp[m];
                if (r != curr) { atomicAdd(&dst[(size_t)curr * LVN + lvl], s); s = 0.f; curr = r; }
                s += vv;
            }
            atomicAdd(&dst[(size_t)curr * LVN + lvl], s);
        }
    }
}

// ================= post: lat-band mean only =================
__global__ __launch_bounds__(256)
void post_kernel(const float* __restrict__ agg, short* __restrict__ latb)
{
    const int b = blockIdx.x, tid = threadIdx.x;
    __shared__ float part[256];
    const int j = tid & 127, half = tid >> 7;
    float s = 0.f;
    for (int lon = half * 120; lon < (half + 1) * 120; ++lon)
        s += agg[((size_t)b * NLON + lon) * HD + j];
    part[tid] = s;
    __syncthreads();
    if (tid < 128)
        latb[(size_t)b * HD + tid] = f2b((part[tid] + part[128 + tid]) * (1.0f / NLON));
}

// ================= node kernel: 128-node tiles, 8 waves, 32x32x16 + wind finalize =================
__global__ __launch_bounds__(512, 4)
void node_mfma(const short* __restrict__ hb, const float* __restrict__ h,
               const short* __restrict__ latb,
               const float* __restrict__ bn1, const float* __restrict__ bn2,
               const short* __restrict__ wp, float* __restrict__ out,
               float* __restrict__ aggu, float* __restrict__ aggv,
               const int* __restrict__ off)
{
    __shared__ short T1[128 * 128];    // 32 KB
    const int tid = threadIdx.x, lane = tid & 63, w = tid >> 6;   // 8 waves
    const int rg = w >> 1, cg = w & 1;                             // rg 0..3
    const int r31 = lane & 31, kh = lane >> 5;
    const int mrow = rg * 32 + r31;                                // 0..127
    const int sw = (mrow & 7) << 4;
    const int colbase = cg * 64;
    const int n0 = blockIdx.x * 128;
    const int n = n0 + mrow;
    const int nc = (n < NN) ? n : (NN - 1);
    const short* hp = hb + (size_t)nc * HD + 8 * kh;
    const float* ap = out + (size_t)nc * HD + 8 * kh;   // agg lives in out region
    const short* lp = latb + (size_t)(nc / NLON) * HD + 8 * kh;

    f16v acc[2];
#pragma unroll
    for (int j = 0; j < 2; ++j) {
        float bv = bn1[colbase + j * 32 + r31];
#pragma unroll
        for (int q = 0; q < 16; ++q) acc[j][q] = bv;
    }
    // h part (k 0..127)
#pragma unroll
    for (int s = 0; s < 8; ++s) {
        short8 a = *(const short8*)(hp + s * 16);
#pragma unroll
        for (int j = 0; j < 2; ++j) {
            short8 bfr = *(const short8*)(wp + OFF_WN1 + (size_t)(s * 4 + cg * 2 + j) * 512 + lane * 8);
            acc[j] = __builtin_amdgcn_mfma_f32_32x32x16_bf16(a, bfr, acc[j], 0, 0, 0);
        }
    }
    // agg part (k 128..255), f32 -> bf16 in reg
#pragma unroll
    for (int s = 0; s < 8; ++s) {
        short8 a;
#pragma unroll
        for (int q = 0; q < 8; ++q) a[q] = f2b(ap[s * 16 + q]);
#pragma unroll
        for (int j = 0; j < 2; ++j) {
            short8 bfr = *(const short8*)(wp + OFF_WN1 + (size_t)((s + 8) * 4 + cg * 2 + j) * 512 + lane * 8);
            acc[j] = __builtin_amdgcn_mfma_f32_32x32x16_bf16(a, bfr, acc[j], 0, 0, 0);
        }
    }
    // lat part (k 256..383)
#pragma unroll
    for (int s = 0; s < 8; ++s) {
        short8 a = *(const short8*)(lp + s * 16);
#pragma unroll
        for (int j = 0; j < 2; ++j) {
            short8 bfr = *(const short8*)(wp + OFF_WN1 + (size_t)((s + 16) * 4 + cg * 2 + j) * 512 + lane * 8);
            acc[j] = __builtin_amdgcn_mfma_f32_32x32x16_bf16(a, bfr, acc[j], 0, 0, 0);
        }
    }
    store32<2>(T1, acc, rg, colbase, r31, kh, true);
    __syncthreads();   // Wn2 K spans both cg halves
    gemm32_lds<8, 4, 2>(T1, wp + OFF_WN2, cg * 2, bn2, acc, mrow, colbase, r31, kh, lane);

    // out = acc + h (residual)
#pragma unroll
    for (int j = 0; j < 2; ++j)
#pragma unroll
        for (int reg = 0; reg < 16; ++reg) {
            int row = rg * 32 + (reg & 3) + 8 * (reg >> 2) + 4 * kh;
            int gn = n0 + row;
            if (gn < NN) {
                int col = colbase + j * 32 + r31;
                out[(size_t)gn * HD + col] = acc[j][reg] + h[(size_t)gn * HD + col];
            }
        }

    // ---- fused wind finalize (grid-stride; independent of the GEMM above) ----
    for (int tt = blockIdx.x * 512 + tid; tt < NN * LVN; tt += gridDim.x * 512) {
        int nn2 = tt / LVN;
        float c = fmaxf((float)(off[nn2 + 1] - off[nn2]), 1.f);
        float xu = aggu[tt] / c, xv = aggv[tt] / c;
        aggu[tt] = fminf(fmaxf(xu, -100.f), 100.f);
        aggv[tt] = fminf(fmaxf(xv, -100.f), 100.f);
    }
}

extern "C" void kernel_launch(void* const* d_in, const int* in_sizes, int n_in,
                              void* d_out, int out_size, void* d_ws, size_t ws_size,
                              hipStream_t stream)
{
    const float* h   = (const float*)d_in[0];
    const float* u   = (const float*)d_in[1];
    const float* v   = (const float*)d_in[2];
    const float* ea  = (const float*)d_in[3];
    const float* We1 = (const float*)d_in[4];
    const float* be1 = (const float*)d_in[5];
    const float* We2 = (const float*)d_in[6];
    const float* be2 = (const float*)d_in[7];
    const float* Wn1 = (const float*)d_in[8];
    const float* bn1 = (const float*)d_in[9];
    const float* Wn2 = (const float*)d_in[10];
    const float* bn2 = (const float*)d_in[11];
    const float* Wc1 = (const float*)d_in[12];
    const float* bc1 = (const float*)d_in[13];
    const float* Wcl = (const float*)d_in[14];
    const int*   eidx = (const int*)d_in[15];

    float* out  = (float*)d_out;
    float* agg  = out;                       // [NN,HD]: agg accum, then h_out
    float* aggu = out + (size_t)NN * HD;
    float* aggv = aggu + (size_t)NN * LVN;

    // ---- workspace layout (no overlaps, ~16 MB) ----
    char* p = (char*)d_ws;
    short* wp  = (short*)p;                  p += (size_t)WP_SHORTS * 2;
    int*   off = (int*)p;                    p += (size_t)(NN + 1) * 4;
    p = (char*)(((size_t)p + 15) & ~(size_t)15);
    short* hb  = (short*)p;                  p += (size_t)NN * HD * 2;
    short* uvb = (short*)p;                  p += (size_t)NN * 40 * 2;
    short* latb = (short*)p;                 p += (size_t)NLAT * HD * 2;
    p = (char*)(((size_t)p + 15) & ~(size_t)15);
    int*   rows_r = (int*)p;                 p += (size_t)EE * 4;
    int*   cols_r = (int*)p;                 p += (size_t)EE * 4;
    float* ear    = (float*)p;               p += (size_t)EE * 4;
    p = (char*)(((size_t)p + 15) & ~(size_t)15);
    int*   cnt = (int*)p;                    p += (size_t)NN * 4;
    int*   cur = (int*)p;

    hipMemsetAsync(d_out, 0, (size_t)out_size * sizeof(float), stream);
    hipMemsetAsync(cnt, 0, (size_t)2 * NN * sizeof(int), stream);

    setup_kernel<<<SB_HIST + SB_HCAST + SB_UV + SB_WP, 256, 0, stream>>>(
        eidx, cnt, h, hb, u, v, uvb, We1, We2, Wc1, Wcl, Wn1, Wn2, wp);
    scan_kernel<<<1, 1024, 0, stream>>>(cnt, off);
    scatter_kernel<<<EE / 256, 256, 0, stream>>>(eidx, ea, off, cur,
                                                 rows_r, cols_r, ear);

    edge_mfma<<<EE / 64, 256, 0, stream>>>(hb, uvb, rows_r, cols_r, ear,
                                           be1, be2, bc1, wp, agg, aggu, aggv);

    post_kernel<<<NLAT, 256, 0, stream>>>(agg, latb);

    node_mfma<<<(NN + 127) / 128, 512, 0, stream>>>(hb, h, latb, bn1, bn2, wp,
                                                    agg, aggu, aggv, off);
}

// Round 15
// 286.770 us; speedup vs baseline: 1.1996x; 1.0011x over previous
//
#include <hip/hip_runtime.h>
#include <hip/hip_bf16.h>
#include <math.h>

#define NN   29040
#define NLAT 121
#define NLON 240
#define HD   128
#define LVN  11
#define EE   464640

typedef __attribute__((ext_vector_type(8))) short short8;
typedef __attribute__((ext_vector_type(16))) float f16v;

// packed-weight offsets (in shorts) inside wp buffer
#define OFF_WE1 0          // 20 kf x 4 nf  = 80 frags (1 KB each)
#define OFF_WE2 40960      // 8 x 4 = 32
#define OFF_WC1 57344      // 8 x 4 = 32
#define OFF_WCL 73728      // 8 x 1 = 8
#define OFF_WN1 77824      // 24 x 4 = 96
#define OFF_WN2 126976     // 8 x 4 = 32
#define WP_SHORTS 143360

__device__ inline short f2b(float x) {
    union { __hip_bfloat16 b; short s; } v;
    v.b = __float2bfloat16(x);
    return v.s;
}
__device__ inline float b2f(unsigned short b) {
    union { unsigned u; float f; } v; v.u = ((unsigned)b) << 16;
    return v.f;
}

// ================= hist (standalone: gates scan; setup roles moved to scatter) ====
__global__ __launch_bounds__(256)
void hist_kernel(const int* __restrict__ eidx, int* __restrict__ cnt)
{
    int e = blockIdx.x * 256 + threadIdx.x;
    atomicAdd(&cnt[eidx[e]], 1);
}

// ================= CSR scan =================
__global__ __launch_bounds__(1024)
void scan_kernel(const int* __restrict__ cnt, int* __restrict__ off)
{
    __shared__ int part[1024];
    const int tid = threadIdx.x;
    const int CH = 29;
    int lo = tid * CH, hi = min(lo + CH, NN);
    int s = 0;
    for (int i = lo; i < hi; ++i) s += cnt[i];
    part[tid] = s;
    __syncthreads();
    for (int d = 1; d < 1024; d <<= 1) {
        int vv = (tid >= d) ? part[tid - d] : 0;
        __syncthreads();
        part[tid] += vv;
        __syncthreads();
    }
    int run = (tid == 0) ? 0 : part[tid - 1];
    for (int i = lo; i < hi; ++i) { off[i] = run; run += cnt[i]; }
    if (tid == 1023) off[NN] = run;
}

// ================= fused scatter | h-cast | uv-prep | weight-pack =================
// scatter's random fire-and-forget writes overlap the independent setup roles
// (they only gate edge_mfma, not scan) — removes the serialized setup pass.
#define SS_SCAT  1815
#define SS_HCAST 1815
#define SS_UV    114
#define SS_WP    70

__global__ __launch_bounds__(256)
void scatter_setup(const int* __restrict__ eidx, const float* __restrict__ ea,
                   const int* __restrict__ off, int* __restrict__ cur,
                   int* __restrict__ rows_r, int* __restrict__ cols_r,
                   float* __restrict__ ear,
                   const float* __restrict__ h, short* __restrict__ hb,
                   const float* __restrict__ u, const float* __restrict__ v,
                   short* __restrict__ uvb,
                   const float* __restrict__ We1, const float* __restrict__ We2,
                   const float* __restrict__ Wc1, const float* __restrict__ Wcl,
                   const float* __restrict__ Wn1, const float* __restrict__ Wn2,
                   short* __restrict__ wp)
{
    const int b = blockIdx.x, tid = threadIdx.x;
    if (b < SS_SCAT) {
        int e = b * 256 + tid;
        int row = eidx[e];
        int col = eidx[EE + e];
        float a = ea[e];
        int p = atomicAdd(&cur[row], 1);
        int idx = off[row] + p;
        rows_r[idx] = row;
        cols_r[idx] = col;
        ear[idx] = a;
        return;
    }
    if (b < SS_SCAT + SS_HCAST) {
        int idx = (b - SS_SCAT) * 256 + tid;          // 8 elems each
        const float4* hf = (const float4*)h;
        float4 a = hf[idx * 2], c = hf[idx * 2 + 1];
        short8 o;
        o[0] = f2b(a.x); o[1] = f2b(a.y); o[2] = f2b(a.z); o[3] = f2b(a.w);
        o[4] = f2b(c.x); o[5] = f2b(c.y); o[6] = f2b(c.z); o[7] = f2b(c.w);
        ((short8*)hb)[idx] = o;
        return;
    }
    if (b < SS_SCAT + SS_HCAST + SS_UV) {
        int n = (b - SS_SCAT - SS_HCAST) * 256 + tid;
        if (n >= NN) return;
        // compact bf16 record, 40 shorts = 80B:
        // [0..10]=u/s  [11..21]=v/s  [22..32]=s  [33]=|u|  [34]=|v|  [35..39]=0
        short* r = uvb + (size_t)n * 40;
        float un = 0.f, vn = 0.f;
#pragma unroll
        for (int l = 0; l < LVN; ++l) {
            float uu = u[n * LVN + l], vv = v[n * LVN + l];
            float s = sqrtf(uu * uu + vv * vv);
            r[l]      = f2b(uu / s);
            r[11 + l] = f2b(vv / s);
            r[22 + l] = f2b(s);
            un += uu * uu; vn += vv * vv;
        }
        r[33] = f2b(sqrtf(un));
        r[34] = f2b(sqrtf(vn));
        r[35] = 0; r[36] = 0; r[37] = 0; r[38] = 0; r[39] = 0;
        return;
    }
    // ---- weight pack for 32x32x16 MFMA B-fragments ----
    // lane l, elem i -> k = kf*16 + 8*(l>>5) + i ; n = nf*32 + (l&31)
    {
        int fg = (b - SS_SCAT - SS_HCAST - SS_UV) * 4 + (tid >> 6);   // 0..279
        const int l = tid & 63;
        int kind, f, base;
        if (fg < 80)       { kind = 0; f = fg;       base = OFF_WE1; }   // 20x4
        else if (fg < 112) { kind = 1; f = fg - 80;  base = OFF_WE2; }   // 8x4
        else if (fg < 144) { kind = 2; f = fg - 112; base = OFF_WC1; }   // 8x4
        else if (fg < 152) { kind = 3; f = fg - 144; base = OFF_WCL; }   // 8x1
        else if (fg < 248) { kind = 4; f = fg - 152; base = OFF_WN1; }   // 24x4
        else               { kind = 5; f = fg - 248; base = OFF_WN2; }   // 8x4
        const int nfw = (kind == 3) ? 1 : 4;
        const int kf = f / nfw, nf = f % nfw;
        short* dst = wp + base + (size_t)f * 512 + l * 8;
        for (int i = 0; i < 8; ++i) {
            int k = kf * 16 + ((l >> 5) << 3) + i;
            int n = nf * 32 + (l & 31);
            float val = 0.f;
            if (kind == 0) {
                int r = (k < 33) ? (256 + k) : (k == 33 ? 289 : (k < 64 ? -1 : k - 64));
                if (r >= 0) val = We1[r * HD + n];
            } else if (kind == 1) val = We2[k * HD + n];
            else if (kind == 2)  val = Wc1[k * HD + n];
            else if (kind == 3)  { if (n < 22) val = Wcl[k * 22 + n]; }
            else if (kind == 4)  val = Wn1[k * HD + n];
            else                 val = Wn2[k * HD + n];
            dst[i] = f2b(val);
        }
    }
}

// ================= 32x32x16 GEMM helpers =================
// A row = mrow, k = kf*16 + 8*(lane>>5) + i.
// C: col = lane&31, row = (reg&3) + 8*(reg>>2) + 4*(lane>>5)   [HW-verified m74/m101]
template<int KF, int NFL, int NJ>
__device__ inline void gemm32_lds(const short* At, const short* Wp, int nf0,
                                  const float* bias, f16v* acc,
                                  int mrow, int colbase, int r31, int kh, int lane)
{
    const char* arow = (const char*)At + mrow * 256;
    const int sw = (mrow & 7) << 4;
#pragma unroll
    for (int j = 0; j < NJ; ++j) {
        float bv = bias ? bias[colbase + j * 32 + r31] : 0.f;
#pragma unroll
        for (int q = 0; q < 16; ++q) acc[j][q] = bv;
    }
#pragma unroll
    for (int kf = 0; kf < KF; ++kf) {
        short8 a = *(const short8*)(arow + ((kf * 32 + 16 * kh) ^ sw));
#pragma unroll
        for (int j = 0; j < NJ; ++j) {
            short8 bfr = *(const short8*)(Wp + (size_t)(kf * NFL + nf0 + j) * 512 + lane * 8);
            acc[j] = __builtin_amdgcn_mfma_f32_32x32x16_bf16(a, bfr, acc[j], 0, 0, 0);
        }
    }
}

// store C (optionally relu) as bf16 row-major tile, 256B rows, XOR-swizzled
template<int NJ>
__device__ inline void store32(short* tile, const f16v* acc, int rg, int colbase,
                               int r31, int kh, bool relu)
{
#pragma unroll
    for (int j = 0; j < NJ; ++j)
#pragma unroll
        for (int reg = 0; reg < 16; ++reg) {
            int row = rg * 32 + (reg & 3) + 8 * (reg >> 2) + 4 * kh;
            int cb2 = (colbase + j * 32 + r31) * 2;
            float vv = acc[j][reg];
            if (relu) vv = fmaxf(vv, 0.f);
            *(short*)((char*)tile + row * 256 + (cb2 ^ ((row & 7) << 4))) = f2b(vv);
        }
}

// ================= edge kernel: 64-edge tiles, 32x32x16 MFMA =================
// (256,4) — measured sweet spot (r10/r12). Index/ea loads coalesced (r14).
// NEW: bijective XCD swizzle (m204; nwg=7260, q=907, r=4) so CSR-adjacent
// tiles (sharing h[row] panels + index lines) land on the same XCD's L2.
__global__ __launch_bounds__(256, 4)
void edge_mfma(const short* __restrict__ hb, const short* __restrict__ uvb,
               const int* __restrict__ rows_r, const int* __restrict__ cols_r,
               const float* __restrict__ ear,
               const float* __restrict__ be1, const float* __restrict__ be2,
               const float* __restrict__ bc1,
               const short* __restrict__ wp,
               float* __restrict__ agg, float* __restrict__ aggu,
               float* __restrict__ aggv)
{
    __shared__ short Twd[64 * 64];     // 8 KB wd tile (128B rows); later O22 f32 overlay
    __shared__ short T1[64 * 128];     // 16 KB tile (256B rows)
    __shared__ int   rows_s[64];
    __shared__ float radu_s[64], radv_s[64];

    const int tid = threadIdx.x, lane = tid & 63, w = tid >> 6;
    const int rg = w >> 1, cg = w & 1;
    // bijective XCD swizzle: tiles 0..7259, q=907, r=4
    const int bid = blockIdx.x;
    const int xcd = bid & 7, o = bid >> 3;
    const int tbase = (xcd < 4) ? xcd * 908 : 4 * 908 + (xcd - 4) * 907;
    const int e0 = (tbase + o) * 64;
    const int r31 = lane & 31, kh = lane >> 5;
    const int mrow = rg * 32 + r31;
    const int sw = (mrow & 7) << 4;
    const int colbase = cg * 64;

    // own-row gather pointers — index loads are coalesced
    int rowm = rows_r[e0 + mrow], colm = cols_r[e0 + mrow];
    const short* hr = hb + (size_t)rowm * HD + 8 * kh;
    const short* hc = hb + (size_t)colm * HD + 8 * kh;

    // ---- wd tile build (block-wide, 4 threads per row); uvb is bf16 ----
    {
        const int m2 = tid >> 2, q = tid & 3;
        const int sw2 = (m2 & 7) << 4;
        int row2 = rows_r[e0 + m2], col2 = cols_r[e0 + m2];
        const short* rc = uvb + (size_t)col2 * 40;
        const short* rr = uvb + (size_t)row2 * 40;
        char* arow = (char*)(Twd + m2 * 64);
        short8 z = {0, 0, 0, 0, 0, 0, 0, 0};
        *(short8*)(arow + q * 32) = z;
        *(short8*)(arow + q * 32 + 16) = z;
        for (int l = q; l < LVN; l += 4) {
            float rel = b2f((unsigned short)rc[l]) * b2f((unsigned short)rr[l])
                      + b2f((unsigned short)rc[11 + l]) * b2f((unsigned short)rr[11 + l]);
            *(short*)(arow + ((2 * l) ^ sw2))        = f2b(rel);
            *(short*)(arow + ((2 * (11 + l)) ^ sw2)) = rc[22 + l];   // already bf16
            *(short*)(arow + ((2 * (22 + l)) ^ sw2)) = rr[22 + l];
        }
        if (q == 0) {
            rows_s[m2] = row2;
            radu_s[m2] = b2f((unsigned short)rc[33]);
            radv_s[m2] = b2f((unsigned short)rc[34]);
        }
        if (q == 3) *(short*)(arow + ((2 * 33) ^ sw2)) = f2b(ear[e0 + m2]);
    }
    __syncthreads();   // B1: Twd/rows_s/rad visible

    // ==== edge MLP layer 1: A = [wd(k 0..63) | h_row(64..191) | h_col(192..319)] ====
    f16v acc[2];
#pragma unroll
    for (int j = 0; j < 2; ++j) {
        float bv = be1[colbase + j * 32 + r31];
#pragma unroll
        for (int q = 0; q < 16; ++q) acc[j][q] = bv;
    }
    {
        const char* awd = (const char*)(Twd + mrow * 64);
#pragma unroll
        for (int kf = 0; kf < 4; ++kf) {
            short8 a = *(const short8*)(awd + ((kf * 32 + 16 * kh) ^ sw));
#pragma unroll
            for (int j = 0; j < 2; ++j) {
                short8 bfr = *(const short8*)(wp + OFF_WE1 + (size_t)(kf * 4 + cg * 2 + j) * 512 + lane * 8);
                acc[j] = __builtin_amdgcn_mfma_f32_32x32x16_bf16(a, bfr, acc[j], 0, 0, 0);
            }
        }
#pragma unroll
        for (int s = 0; s < 8; ++s) {
            short8 a = *(const short8*)(hr + s * 16);
#pragma unroll
            for (int j = 0; j < 2; ++j) {
                short8 bfr = *(const short8*)(wp + OFF_WE1 + (size_t)((s + 4) * 4 + cg * 2 + j) * 512 + lane * 8);
                acc[j] = __builtin_amdgcn_mfma_f32_32x32x16_bf16(a, bfr, acc[j], 0, 0, 0);
            }
        }
#pragma unroll
        for (int s = 0; s < 8; ++s) {
            short8 a = *(const short8*)(hc + s * 16);
#pragma unroll
            for (int j = 0; j < 2; ++j) {
                short8 bfr = *(const short8*)(wp + OFF_WE1 + (size_t)((s + 12) * 4 + cg * 2 + j) * 512 + lane * 8);
                acc[j] = __builtin_amdgcn_mfma_f32_32x32x16_bf16(a, bfr, acc[j], 0, 0, 0);
            }
        }
    }
    store32<2>(T1, acc, rg, colbase, r31, kh, true);    // Y1
    __syncthreads();   // B2: Y1 complete

    // ==== edge MLP layer 2 (K=128 spans both cg halves of Y1) ====
    gemm32_lds<8, 4, 2>(T1, wp + OFF_WE2, cg * 2, be2, acc, mrow, colbase, r31, kh, lane);
    __syncthreads();   // B2.5: all Y1 reads done before EF overwrites
    store32<2>(T1, acc, rg, colbase, r31, kh, true);    // EF
    __syncthreads();   // B3: EF complete

    // ==== coord MLP layer 1 (reads EF, all cols) ====
    gemm32_lds<8, 4, 2>(T1, wp + OFF_WC1, cg * 2, bc1, acc, mrow, colbase, r31, kh, lane);

    // ==== agg: segmented reduce over sorted rows (own rg rows, own cg cols) ====
    {
        const int col = colbase + lane;
        const int m0 = rg * 32;
        int curr = rows_s[m0];
        float s = 0.f;
        for (int m = m0; m < m0 + 32; ++m) {
            int r = rows_s[m];
            float vv = b2f(*(const unsigned short*)((const char*)T1 + m * 256 + (((col & 127) * 2) ^ ((m & 7) << 4))));
            if (r != curr) { atomicAdd(&agg[(size_t)curr * HD + (col & 127)], s); s = 0.f; curr = r; }
            s += vv;
        }
        atomicAdd(&agg[(size_t)curr * HD + (col & 127)], s);
    }
    __syncthreads();   // B4: EF reads (C1 gemm + reduce) done
    store32<2>(T1, acc, rg, colbase, r31, kh, true);    // C1
    __syncthreads();   // B5: C1 complete

    // ==== coord final layer (cg=0 waves; N=22 fits one 32-col frag) + wind ====
    if (cg == 0) {
        gemm32_lds<8, 1, 1>(T1, wp + OFF_WCL, 0, (const float*)nullptr, acc, mrow, 0, r31, kh, lane);
        float* O22 = (float*)Twd;               // 64x32 f32 overlay (wd dead)
#pragma unroll
        for (int reg = 0; reg < 16; ++reg) {
            int row = rg * 32 + (reg & 3) + 8 * (reg >> 2) + 4 * kh;
            O22[row * 32 + r31] = acc[0][reg];
        }
        // wind segmented reduce: 16-row chains (rg, kh) over own-wave rows
        const int c = r31;
        if (c < 22) {
            const bool isU = c < LVN;
            const int lvl = isU ? c : c - LVN;
            float* dst = isU ? aggu : aggv;
            const float* radp = isU ? radu_s : radv_s;
            const int m0 = rg * 32 + kh * 16;
            int curr = rows_s[m0]; float s = 0.f;
            for (int m = m0; m < m0 + 16; ++m) {
                int r = rows_s[m];
                float vv = O22[m * 32 + c] * radp[m];
                if (r != curr) { atomicAdd(&dst[(size_t)curr * LVN + lvl], s); s = 0.f; curr = r; }
                s += vv;
            }
            atomicAdd(&dst[(size_t)curr * LVN + lvl], s);
        }
    }
}

// ================= post: lat-band mean only =================
__global__ __launch_bounds__(256)
void post_kernel(const float* __restrict__ agg, short* __restrict__ latb)
{
    const int b = blockIdx.x, tid = threadIdx.x;
    __shared__ float part[256];
    const int j = tid & 127, half = tid >> 7;
    float s = 0.f;
    for (int lon = half * 120; lon < (half + 1) * 120; ++lon)
        s += agg[((size_t)b * NLON + lon) * HD + j];
    part[tid] = s;
    __syncthreads();
    if (tid < 128)
        latb[(size_t)b * HD + tid] = f2b((part[tid] + part[128 + tid]) * (1.0f / NLON));
}

// ================= node kernel: 128-node tiles, 8 waves, 32x32x16 + wind finalize =================
__global__ __launch_bounds__(512, 4)
void node_mfma(const short* __restrict__ hb, const float* __restrict__ h,
               const short* __restrict__ latb,
               const float* __restrict__ bn1, const float* __restrict__ bn2,
               const short* __restrict__ wp, float* __restrict__ out,
               float* __restrict__ aggu, float* __restrict__ aggv,
               const int* __restrict__ cnt)
{
    __shared__ short T1[128 * 128];    // 32 KB
    const int tid = threadIdx.x, lane = tid & 63, w = tid >> 6;   // 8 waves
    const int rg = w >> 1, cg = w & 1;                             // rg 0..3
    const int r31 = lane & 31, kh = lane >> 5;
    const int mrow = rg * 32 + r31;                                // 0..127
    const int sw = (mrow & 7) << 4;
    const int colbase = cg * 64;
    const int n0 = blockIdx.x * 128;
    const int n = n0 + mrow;
    const int nc = (n < NN) ? n : (NN - 1);
    const short* hp = hb + (size_t)nc * HD + 8 * kh;
    const float* ap = out + (size_t)nc * HD + 8 * kh;   // agg lives in out region
    const short* lp = latb + (size_t)(nc / NLON) * HD + 8 * kh;

    f16v acc[2];
#pragma unroll
    for (int j = 0; j < 2; ++j) {
        float bv = bn1[colbase + j * 32 + r31];
#pragma unroll
        for (int q = 0; q < 16; ++q) acc[j][q] = bv;
    }
    // h part (k 0..127)
#pragma unroll
    for (int s = 0; s < 8; ++s) {
        short8 a = *(const short8*)(hp + s * 16);
#pragma unroll
        for (int j = 0; j < 2; ++j) {
            short8 bfr = *(const short8*)(wp + OFF_WN1 + (size_t)(s * 4 + cg * 2 + j) * 512 + lane * 8);
            acc[j] = __builtin_amdgcn_mfma_f32_32x32x16_bf16(a, bfr, acc[j], 0, 0, 0);
        }
    }
    // agg part (k 128..255), f32 -> bf16 in reg
#pragma unroll
    for (int s = 0; s < 8; ++s) {
        short8 a;
#pragma unroll
        for (int q = 0; q < 8; ++q) a[q] = f2b(ap[s * 16 + q]);
#pragma unroll
        for (int j = 0; j < 2; ++j) {
            short8 bfr = *(const short8*)(wp + OFF_WN1 + (size_t)((s + 8) * 4 + cg * 2 + j) * 512 + lane * 8);
            acc[j] = __builtin_amdgcn_mfma_f32_32x32x16_bf16(a, bfr, acc[j], 0, 0, 0);
        }
    }
    // lat part (k 256..383)
#pragma unroll
    for (int s = 0; s < 8; ++s) {
        short8 a = *(const short8*)(lp + s * 16);
#pragma unroll
        for (int j = 0; j < 2; ++j) {
            short8 bfr = *(const short8*)(wp + OFF_WN1 + (size_t)((s + 16) * 4 + cg * 2 + j) * 512 + lane * 8);
            acc[j] = __builtin_amdgcn_mfma_f32_32x32x16_bf16(a, bfr, acc[j], 0, 0, 0);
        }
    }
    store32<2>(T1, acc, rg, colbase, r31, kh, true);
    __syncthreads();   // Wn2 K spans both cg halves
    gemm32_lds<8, 4, 2>(T1, wp + OFF_WN2, cg * 2, bn2, acc, mrow, colbase, r31, kh, lane);

    // out = acc + h (residual)
#pragma unroll
    for (int j = 0; j < 2; ++j)
#pragma unroll
        for (int reg = 0; reg < 16; ++reg) {
            int row = rg * 32 + (reg & 3) + 8 * (reg >> 2) + 4 * kh;
            int gn = n0 + row;
            if (gn < NN) {
                int col = colbase + j * 32 + r31;
                out[(size_t)gn * HD + col] = acc[j][reg] + h[(size_t)gn * HD + col];
            }
        }

    // ---- fused wind finalize (grid-stride; independent of the GEMM above) ----
    for (int tt = blockIdx.x * 512 + tid; tt < NN * LVN; tt += gridDim.x * 512) {
        int nn2 = tt / LVN;
        float c = fmaxf((float)cnt[nn2], 1.f);
        float xu = aggu[tt] / c, xv = aggv[tt] / c;
        aggu[tt] = fminf(fmaxf(xu, -100.f), 100.f);
        aggv[tt] = fminf(fmaxf(xv, -100.f), 100.f);
    }
}

extern "C" void kernel_launch(void* const* d_in, const int* in_sizes, int n_in,
                              void* d_out, int out_size, void* d_ws, size_t ws_size,
                              hipStream_t stream)
{
    const float* h   = (const float*)d_in[0];
    const float* u   = (const float*)d_in[1];
    const float* v   = (const float*)d_in[2];
    const float* ea  = (const float*)d_in[3];
    const float* We1 = (const float*)d_in[4];
    const float* be1 = (const float*)d_in[5];
    const float* We2 = (const float*)d_in[6];
    const float* be2 = (const float*)d_in[7];
    const float* Wn1 = (const float*)d_in[8];
    const float* bn1 = (const float*)d_in[9];
    const float* Wn2 = (const float*)d_in[10];
    const float* bn2 = (const float*)d_in[11];
    const float* Wc1 = (const float*)d_in[12];
    const float* bc1 = (const float*)d_in[13];
    const float* Wcl = (const float*)d_in[14];
    const int*   eidx = (const int*)d_in[15];

    float* out  = (float*)d_out;
    float* agg  = out;                       // [NN,HD]: agg accum, then h_out
    float* aggu = out + (size_t)NN * HD;
    float* aggv = aggu + (size_t)NN * LVN;

    // ---- workspace layout (no overlaps, ~16 MB) ----
    char* p = (char*)d_ws;
    short* wp  = (short*)p;                  p += (size_t)WP_SHORTS * 2;
    int*   off = (int*)p;                    p += (size_t)(NN + 1) * 4;
    p = (char*)(((size_t)p + 15) & ~(size_t)15);
    short* hb  = (short*)p;                  p += (size_t)NN * HD * 2;
    short* uvb = (short*)p;                  p += (size_t)NN * 40 * 2;
    short* latb = (short*)p;                 p += (size_t)NLAT * HD * 2;
    p = (char*)(((size_t)p + 15) & ~(size_t)15);
    int*   rows_r = (int*)p;                 p += (size_t)EE * 4;
    int*   cols_r = (int*)p;                 p += (size_t)EE * 4;
    float* ear    = (float*)p;               p += (size_t)EE * 4;
    p = (char*)(((size_t)p + 15) & ~(size_t)15);
    int*   cnt = (int*)p;                    p += (size_t)NN * 4;
    int*   cur = (int*)p;

    hipMemsetAsync(d_out, 0, (size_t)out_size * sizeof(float), stream);
    hipMemsetAsync(cnt, 0, (size_t)2 * NN * sizeof(int), stream);

    hist_kernel<<<EE / 256, 256, 0, stream>>>(eidx, cnt);
    scan_kernel<<<1, 1024, 0, stream>>>(cnt, off);
    scatter_setup<<<SS_SCAT + SS_HCAST + SS_UV + SS_WP, 256, 0, stream>>>(
        eidx, ea, off, cur, rows_r, cols_r, ear,
        h, hb, u, v, uvb, We1, We2, Wc1, Wcl, Wn1, Wn2, wp);

    edge_mfma<<<EE / 64, 256, 0, stream>>>(hb, uvb, rows_r, cols_r, ear,
                                           be1, be2, bc1, wp, agg, aggu, aggv);

    post_kernel<<<NLAT, 256, 0, stream>>>(agg, latb);

    node_mfma<<<(NN + 127) / 128, 512, 0, stream>>>(hb, h, latb, bn1, bn2, wp,
                                                    agg, aggu, aggv, cnt);
}

// Round 16
// 282.832 us; speedup vs baseline: 1.2163x; 1.0139x over previous
//
#include <hip/hip_runtime.h>
#include <hip/hip_bf16.h>
#include <math.h>

#define NN   29040
#define NLAT 121
#define NLON 240
#define HD   128
#define LVN  11
#define EE   464640

typedef __attribute__((ext_vector_type(8))) short short8;
typedef __attribute__((ext_vector_type(16))) float f16v;

// packed-weight offsets (in shorts) inside wp buffer
#define OFF_WE1 0          // 20 kf x 4 nf  = 80 frags (1 KB each)
#define OFF_WE2 40960      // 8 x 4 = 32
#define OFF_WC1 57344      // 8 x 4 = 32
#define OFF_WCL 73728      // 8 x 1 = 8
#define OFF_WN1 77824      // 24 x 4 = 96
#define OFF_WN2 126976     // 8 x 4 = 32
#define WP_SHORTS 143360

__device__ inline short f2b(float x) {
    union { __hip_bfloat16 b; short s; } v;
    v.b = __float2bfloat16(x);
    return v.s;
}
__device__ inline float b2f(unsigned short b) {
    union { unsigned u; float f; } v; v.u = ((unsigned)b) << 16;
    return v.f;
}
__device__ inline unsigned pk2(float lo, float hi) {
    return ((unsigned)(unsigned short)f2b(hi) << 16) | (unsigned short)f2b(lo);
}
__device__ inline float asf(unsigned u) {
    union { unsigned u; float f; } v; v.u = u;
    return v.f;
}

// ================= hist =================
__global__ __launch_bounds__(256)
void hist_kernel(const int* __restrict__ eidx, int* __restrict__ cnt)
{
    int e = blockIdx.x * 256 + threadIdx.x;
    atomicAdd(&cnt[eidx[e]], 1);
}

// ================= CSR scan =================
__global__ __launch_bounds__(1024)
void scan_kernel(const int* __restrict__ cnt, int* __restrict__ off)
{
    __shared__ int part[1024];
    const int tid = threadIdx.x;
    const int CH = 29;
    int lo = tid * CH, hi = min(lo + CH, NN);
    int s = 0;
    for (int i = lo; i < hi; ++i) s += cnt[i];
    part[tid] = s;
    __syncthreads();
    for (int d = 1; d < 1024; d <<= 1) {
        int vv = (tid >= d) ? part[tid - d] : 0;
        __syncthreads();
        part[tid] += vv;
        __syncthreads();
    }
    int run = (tid == 0) ? 0 : part[tid - 1];
    for (int i = lo; i < hi; ++i) { off[i] = run; run += cnt[i]; }
    if (tid == 1023) off[NN] = run;
}

// ================= fused scatter | h-cast | uv-prep | weight-pack =================
#define SS_SCAT  1815
#define SS_HCAST 1815
#define SS_UV    114
#define SS_WP    70

__global__ __launch_bounds__(256)
void scatter_setup(const int* __restrict__ eidx, const float* __restrict__ ea,
                   const int* __restrict__ off, int* __restrict__ cur,
                   int* __restrict__ rows_r, int* __restrict__ cols_r,
                   float* __restrict__ ear,
                   const float* __restrict__ h, short* __restrict__ hb,
                   const float* __restrict__ u, const float* __restrict__ v,
                   short* __restrict__ uvb,
                   const float* __restrict__ We1, const float* __restrict__ We2,
                   const float* __restrict__ Wc1, const float* __restrict__ Wcl,
                   const float* __restrict__ Wn1, const float* __restrict__ Wn2,
                   short* __restrict__ wp)
{
    const int b = blockIdx.x, tid = threadIdx.x;
    if (b < SS_SCAT) {
        int e = b * 256 + tid;
        int row = eidx[e];
        int col = eidx[EE + e];
        float a = ea[e];
        int p = atomicAdd(&cur[row], 1);
        int idx = off[row] + p;
        rows_r[idx] = row;
        cols_r[idx] = col;
        ear[idx] = a;
        return;
    }
    if (b < SS_SCAT + SS_HCAST) {
        int idx = (b - SS_SCAT) * 256 + tid;          // 8 elems each
        const float4* hf = (const float4*)h;
        float4 a = hf[idx * 2], c = hf[idx * 2 + 1];
        short8 o;
        o[0] = f2b(a.x); o[1] = f2b(a.y); o[2] = f2b(a.z); o[3] = f2b(a.w);
        o[4] = f2b(c.x); o[5] = f2b(c.y); o[6] = f2b(c.z); o[7] = f2b(c.w);
        ((short8*)hb)[idx] = o;
        return;
    }
    if (b < SS_SCAT + SS_HCAST + SS_UV) {
        int n = (b - SS_SCAT - SS_HCAST) * 256 + tid;
        if (n >= NN) return;
        // compact bf16 record, 40 shorts = 80B:
        // [0..10]=u/s  [11..21]=v/s  [22..32]=s  [33]=|u|  [34]=|v|  [35..39]=0
        short* r = uvb + (size_t)n * 40;
        float un = 0.f, vn = 0.f;
#pragma unroll
        for (int l = 0; l < LVN; ++l) {
            float uu = u[n * LVN + l], vv = v[n * LVN + l];
            float s = sqrtf(uu * uu + vv * vv);
            r[l]      = f2b(uu / s);
            r[11 + l] = f2b(vv / s);
            r[22 + l] = f2b(s);
            un += uu * uu; vn += vv * vv;
        }
        r[33] = f2b(sqrtf(un));
        r[34] = f2b(sqrtf(vn));
        r[35] = 0; r[36] = 0; r[37] = 0; r[38] = 0; r[39] = 0;
        return;
    }
    // ---- weight pack for 32x32x16 MFMA B-fragments ----
    // physical slot kp = kf*16 + 8*(l>>5) + i ; n = nf*32 + (l&31)
    // Consumers of PACKED tiles (We2/Wc1/Wcl/Wn2): tile stores pack col pairs
    // (c, c+32) into one u32, so physical short s holds logical col
    // (s&64) + ((s&63)>>1) + ((s&1)<<5) — permute k identically.
    {
        int fg = (b - SS_SCAT - SS_HCAST - SS_UV) * 4 + (tid >> 6);   // 0..279
        const int l = tid & 63;
        int kind, f, base;
        if (fg < 80)       { kind = 0; f = fg;       base = OFF_WE1; }   // 20x4
        else if (fg < 112) { kind = 1; f = fg - 80;  base = OFF_WE2; }   // 8x4
        else if (fg < 144) { kind = 2; f = fg - 112; base = OFF_WC1; }   // 8x4
        else if (fg < 152) { kind = 3; f = fg - 144; base = OFF_WCL; }   // 8x1
        else if (fg < 248) { kind = 4; f = fg - 152; base = OFF_WN1; }   // 24x4
        else               { kind = 5; f = fg - 248; base = OFF_WN2; }   // 8x4
        const int nfw = (kind == 3) ? 1 : 4;
        const int kf = f / nfw, nf = f % nfw;
        const bool perm = (kind == 1) || (kind == 2) || (kind == 3) || (kind == 5);
        short* dst = wp + base + (size_t)f * 512 + l * 8;
        for (int i = 0; i < 8; ++i) {
            int kp = kf * 16 + ((l >> 5) << 3) + i;
            int k;
            if (perm) { int s6 = kp & 63; k = (kp & 64) + (s6 >> 1) + ((s6 & 1) << 5); }
            else k = kp;
            int n = nf * 32 + (l & 31);
            float val = 0.f;
            if (kind == 0) {
                int r = (k < 33) ? (256 + k) : (k == 33 ? 289 : (k < 64 ? -1 : k - 64));
                if (r >= 0) val = We1[r * HD + n];
            } else if (kind == 1) val = We2[k * HD + n];
            else if (kind == 2)  val = Wc1[k * HD + n];
            else if (kind == 3)  { if (n < 22) val = Wcl[k * 22 + n]; }
            else if (kind == 4)  val = Wn1[k * HD + n];
            else                 val = Wn2[k * HD + n];
            dst[i] = f2b(val);
        }
    }
}

// ================= 32x32x16 GEMM helpers =================
// A row = mrow, physical k-slot kp = kf*16 + 8*(lane>>5) + i.
// C: col = lane&31, row = (reg&3) + 8*(reg>>2) + 4*(lane>>5)   [HW-verified m74/m101]
template<int KF, int NFL, int NJ>
__device__ inline void gemm32_lds(const short* At, const short* Wp, int nf0,
                                  const float* bias, f16v* acc,
                                  int mrow, int colbase, int r31, int kh, int lane)
{
    const char* arow = (const char*)At + mrow * 256;
    const int sw = (mrow & 7) << 4;
#pragma unroll
    for (int j = 0; j < NJ; ++j) {
        float bv = bias ? bias[colbase + j * 32 + r31] : 0.f;
#pragma unroll
        for (int q = 0; q < 16; ++q) acc[j][q] = bv;
    }
#pragma unroll
    for (int kf = 0; kf < KF; ++kf) {
        short8 a = *(const short8*)(arow + ((kf * 32 + 16 * kh) ^ sw));
#pragma unroll
        for (int j = 0; j < NJ; ++j) {
            short8 bfr = *(const short8*)(Wp + (size_t)(kf * NFL + nf0 + j) * 512 + lane * 8);
            acc[j] = __builtin_amdgcn_mfma_f32_32x32x16_bf16(a, bfr, acc[j], 0, 0, 0);
        }
    }
}

// packed store: col pairs (c, c+32) from acc[0]/acc[1] (same row) -> one u32.
// physical u32 position p = cg*32 + r31; logical lo col = (p>>5)*64 + (p&31),
// hi col = lo + 32. Consumers use perm'd weights (see pack kernel).
__device__ inline void store_pk32(short* tile, const f16v* acc, int rg, int cg,
                                  int r31, int kh, bool relu)
{
    const int boff = cg * 128 + r31 * 4;
#pragma unroll
    for (int reg = 0; reg < 16; ++reg) {
        int row = rg * 32 + (reg & 3) + 8 * (reg >> 2) + 4 * kh;
        float lo = acc[0][reg], hi = acc[1][reg];
        if (relu) { lo = fmaxf(lo, 0.f); hi = fmaxf(hi, 0.f); }
        *(unsigned*)((char*)tile + row * 256 + (boff ^ ((row & 7) << 4))) = pk2(lo, hi);
    }
}

// ================= edge kernel: 64-edge tiles, 32x32x16 MFMA =================
// (256,4) sweet spot (r10/r12); coalesced CSR payload (r14); XCD swizzle (r15).
// NEW: packed u32 tile stores + paired agg reduce — halves the scalar DS/f2b
// issue streams (the r15-diagnosed issue floor: VALUBusy 33% + DS pipe).
__global__ __launch_bounds__(256, 4)
void edge_mfma(const short* __restrict__ hb, const short* __restrict__ uvb,
               const int* __restrict__ rows_r, const int* __restrict__ cols_r,
               const float* __restrict__ ear,
               const float* __restrict__ be1, const float* __restrict__ be2,
               const float* __restrict__ bc1,
               const short* __restrict__ wp,
               float* __restrict__ agg, float* __restrict__ aggu,
               float* __restrict__ aggv)
{
    __shared__ short Twd[64 * 64];     // 8 KB wd tile (128B rows); later O22 f32 overlay
    __shared__ short T1[64 * 128];     // 16 KB tile (256B rows), packed col-pair layout
    __shared__ int   rows_s[64];
    __shared__ float radu_s[64], radv_s[64];

    const int tid = threadIdx.x, lane = tid & 63, w = tid >> 6;
    const int rg = w >> 1, cg = w & 1;
    // bijective XCD swizzle: tiles 0..7259, q=907, r=4
    const int bid = blockIdx.x;
    const int xcd = bid & 7, o = bid >> 3;
    const int tbase = (xcd < 4) ? xcd * 908 : 4 * 908 + (xcd - 4) * 907;
    const int e0 = (tbase + o) * 64;
    const int r31 = lane & 31, kh = lane >> 5;
    const int mrow = rg * 32 + r31;
    const int sw = (mrow & 7) << 4;
    const int colbase = cg * 64;

    // own-row gather pointers — index loads are coalesced
    int rowm = rows_r[e0 + mrow], colm = cols_r[e0 + mrow];
    const short* hr = hb + (size_t)rowm * HD + 8 * kh;
    const short* hc = hb + (size_t)colm * HD + 8 * kh;

    // ---- wd tile build (block-wide, 4 threads per row); uvb is bf16 ----
    {
        const int m2 = tid >> 2, q = tid & 3;
        const int sw2 = (m2 & 7) << 4;
        int row2 = rows_r[e0 + m2], col2 = cols_r[e0 + m2];
        const short* rc = uvb + (size_t)col2 * 40;
        const short* rr = uvb + (size_t)row2 * 40;
        char* arow = (char*)(Twd + m2 * 64);
        short8 z = {0, 0, 0, 0, 0, 0, 0, 0};
        *(short8*)(arow + q * 32) = z;
        *(short8*)(arow + q * 32 + 16) = z;
        for (int l = q; l < LVN; l += 4) {
            float rel = b2f((unsigned short)rc[l]) * b2f((unsigned short)rr[l])
                      + b2f((unsigned short)rc[11 + l]) * b2f((unsigned short)rr[11 + l]);
            *(short*)(arow + ((2 * l) ^ sw2))        = f2b(rel);
            *(short*)(arow + ((2 * (11 + l)) ^ sw2)) = rc[22 + l];   // already bf16
            *(short*)(arow + ((2 * (22 + l)) ^ sw2)) = rr[22 + l];
        }
        if (q == 0) {
            rows_s[m2] = row2;
            radu_s[m2] = b2f((unsigned short)rc[33]);
            radv_s[m2] = b2f((unsigned short)rc[34]);
        }
        if (q == 3) *(short*)(arow + ((2 * 33) ^ sw2)) = f2b(ear[e0 + m2]);
    }
    __syncthreads();   // B1: Twd/rows_s/rad visible

    // ==== edge MLP layer 1: A = [wd(k 0..63) | h_row(64..191) | h_col(192..319)] ====
    f16v acc[2];
#pragma unroll
    for (int j = 0; j < 2; ++j) {
        float bv = be1[colbase + j * 32 + r31];
#pragma unroll
        for (int q = 0; q < 16; ++q) acc[j][q] = bv;
    }
    {
        const char* awd = (const char*)(Twd + mrow * 64);
#pragma unroll
        for (int kf = 0; kf < 4; ++kf) {
            short8 a = *(const short8*)(awd + ((kf * 32 + 16 * kh) ^ sw));
#pragma unroll
            for (int j = 0; j < 2; ++j) {
                short8 bfr = *(const short8*)(wp + OFF_WE1 + (size_t)(kf * 4 + cg * 2 + j) * 512 + lane * 8);
                acc[j] = __builtin_amdgcn_mfma_f32_32x32x16_bf16(a, bfr, acc[j], 0, 0, 0);
            }
        }
#pragma unroll
        for (int s = 0; s < 8; ++s) {
            short8 a = *(const short8*)(hr + s * 16);
#pragma unroll
            for (int j = 0; j < 2; ++j) {
                short8 bfr = *(const short8*)(wp + OFF_WE1 + (size_t)((s + 4) * 4 + cg * 2 + j) * 512 + lane * 8);
                acc[j] = __builtin_amdgcn_mfma_f32_32x32x16_bf16(a, bfr, acc[j], 0, 0, 0);
            }
        }
#pragma unroll
        for (int s = 0; s < 8; ++s) {
            short8 a = *(const short8*)(hc + s * 16);
#pragma unroll
            for (int j = 0; j < 2; ++j) {
                short8 bfr = *(const short8*)(wp + OFF_WE1 + (size_t)((s + 12) * 4 + cg * 2 + j) * 512 + lane * 8);
                acc[j] = __builtin_amdgcn_mfma_f32_32x32x16_bf16(a, bfr, acc[j], 0, 0, 0);
            }
        }
    }
    store_pk32(T1, acc, rg, cg, r31, kh, true);    // Y1 (packed)
    __syncthreads();   // B2: Y1 complete

    // ==== edge MLP layer 2 (K=128 spans both cg halves of Y1; Wp perm'd) ====
    gemm32_lds<8, 4, 2>(T1, wp + OFF_WE2, cg * 2, be2, acc, mrow, colbase, r31, kh, lane);
    __syncthreads();   // B2.5: all Y1 reads done before EF overwrites
    store_pk32(T1, acc, rg, cg, r31, kh, true);    // EF (packed)
    __syncthreads();   // B3: EF complete

    // ==== coord MLP layer 1 (reads EF; Wp perm'd) ====
    gemm32_lds<8, 4, 2>(T1, wp + OFF_WC1, cg * 2, bc1, acc, mrow, colbase, r31, kh, lane);

    // ==== agg: paired segmented reduce (own rg rows; own cg's 64 cols) ====
    {
        const int p = cg * 32 + (lane & 31);   // u32 position 0..63
        const int rh = lane >> 5;              // row half
        const int n0 = (p >> 5) * 64 + (p & 31), n1 = n0 + 32;
        const int m0 = rg * 32 + rh * 16;
        int curr = rows_s[m0];
        float s0 = 0.f, s1 = 0.f;
        for (int m = m0; m < m0 + 16; ++m) {
            int r = rows_s[m];
            unsigned vv = *(const unsigned*)((const char*)T1 + m * 256 + ((4 * p) ^ ((m & 7) << 4)));
            if (r != curr) {
                atomicAdd(&agg[(size_t)curr * HD + n0], s0);
                atomicAdd(&agg[(size_t)curr * HD + n1], s1);
                s0 = 0.f; s1 = 0.f; curr = r;
            }
            s0 += asf(vv << 16);
            s1 += asf(vv & 0xFFFF0000u);
        }
        atomicAdd(&agg[(size_t)curr * HD + n0], s0);
        atomicAdd(&agg[(size_t)curr * HD + n1], s1);
    }
    __syncthreads();   // B4: EF reads (C1 gemm + reduce) done
    store_pk32(T1, acc, rg, cg, r31, kh, true);    // C1 (packed)
    __syncthreads();   // B5: C1 complete

    // ==== coord final layer (cg=0 waves; Wcl perm'd, N=22 in one frag) + wind ====
    if (cg == 0) {
        gemm32_lds<8, 1, 1>(T1, wp + OFF_WCL, 0, (const float*)nullptr, acc, mrow, 0, r31, kh, lane);
        float* O22 = (float*)Twd;               // 64x32 f32 overlay (wd dead)
#pragma unroll
        for (int reg = 0; reg < 16; ++reg) {
            int row = rg * 32 + (reg & 3) + 8 * (reg >> 2) + 4 * kh;
            O22[row * 32 + r31] = acc[0][reg];
        }
        // wind segmented reduce: 16-row chains (rg, kh) over own-wave rows
        const int c = r31;
        if (c < 22) {
            const bool isU = c < LVN;
            const int lvl = isU ? c : c - LVN;
            float* dst = isU ? aggu : aggv;
            const float* radp = isU ? radu_s : radv_s;
            const int m0 = rg * 32 + kh * 16;
            int curr = rows_s[m0]; float s = 0.f;
            for (int m = m0; m < m0 + 16; ++m) {
                int r = rows_s[m];
                float vv = O22[m * 32 + c] * radp[m];
                if (r != curr) { atomicAdd(&dst[(size_t)curr * LVN + lvl], s); s = 0.f; curr = r; }
                s += vv;
            }
            atomicAdd(&dst[(size_t)curr * LVN + lvl], s);
        }
    }
}

// ================= post: lat-band mean only =================
__global__ __launch_bounds__(256)
void post_kernel(const float* __restrict__ agg, short* __restrict__ latb)
{
    const int b = blockIdx.x, tid = threadIdx.x;
    __shared__ float part[256];
    const int j = tid & 127, half = tid >> 7;
    float s = 0.f;
    for (int lon = half * 120; lon < (half + 1) * 120; ++lon)
        s += agg[((size_t)b * NLON + lon) * HD + j];
    part[tid] = s;
    __syncthreads();
    if (tid < 128)
        latb[(size_t)b * HD + tid] = f2b((part[tid] + part[128 + tid]) * (1.0f / NLON));
}

// ================= node kernel: 128-node tiles, 8 waves, 32x32x16 + wind finalize =================
__global__ __launch_bounds__(512, 4)
void node_mfma(const short* __restrict__ hb, const float* __restrict__ h,
               const short* __restrict__ latb,
               const float* __restrict__ bn1, const float* __restrict__ bn2,
               const short* __restrict__ wp, float* __restrict__ out,
               float* __restrict__ aggu, float* __restrict__ aggv,
               const int* __restrict__ cnt)
{
    __shared__ short T1[128 * 128];    // 32 KB, packed col-pair layout
    const int tid = threadIdx.x, lane = tid & 63, w = tid >> 6;   // 8 waves
    const int rg = w >> 1, cg = w & 1;                             // rg 0..3
    const int r31 = lane & 31, kh = lane >> 5;
    const int mrow = rg * 32 + r31;                                // 0..127
    const int colbase = cg * 64;
    const int n0 = blockIdx.x * 128;
    const int n = n0 + mrow;
    const int nc = (n < NN) ? n : (NN - 1);
    const short* hp = hb + (size_t)nc * HD + 8 * kh;
    const float* ap = out + (size_t)nc * HD + 8 * kh;   // agg lives in out region
    const short* lp = latb + (size_t)(nc / NLON) * HD + 8 * kh;

    f16v acc[2];
#pragma unroll
    for (int j = 0; j < 2; ++j) {
        float bv = bn1[colbase + j * 32 + r31];
#pragma unroll
        for (int q = 0; q < 16; ++q) acc[j][q] = bv;
    }
    // h part (k 0..127)
#pragma unroll
    for (int s = 0; s < 8; ++s) {
        short8 a = *(const short8*)(hp + s * 16);
#pragma unroll
        for (int j = 0; j < 2; ++j) {
            short8 bfr = *(const short8*)(wp + OFF_WN1 + (size_t)(s * 4 + cg * 2 + j) * 512 + lane * 8);
            acc[j] = __builtin_amdgcn_mfma_f32_32x32x16_bf16(a, bfr, acc[j], 0, 0, 0);
        }
    }
    // agg part (k 128..255), f32 -> bf16 in reg
#pragma unroll
    for (int s = 0; s < 8; ++s) {
        short8 a;
#pragma unroll
        for (int q = 0; q < 8; ++q) a[q] = f2b(ap[s * 16 + q]);
#pragma unroll
        for (int j = 0; j < 2; ++j) {
            short8 bfr = *(const short8*)(wp + OFF_WN1 + (size_t)((s + 8) * 4 + cg * 2 + j) * 512 + lane * 8);
            acc[j] = __builtin_amdgcn_mfma_f32_32x32x16_bf16(a, bfr, acc[j], 0, 0, 0);
        }
    }
    // lat part (k 256..383)
#pragma unroll
    for (int s = 0; s < 8; ++s) {
        short8 a = *(const short8*)(lp + s * 16);
#pragma unroll
        for (int j = 0; j < 2; ++j) {
            short8 bfr = *(const short8*)(wp + OFF_WN1 + (size_t)((s + 16) * 4 + cg * 2 + j) * 512 + lane * 8);
            acc[j] = __builtin_amdgcn_mfma_f32_32x32x16_bf16(a, bfr, acc[j], 0, 0, 0);
        }
    }
    store_pk32(T1, acc, rg, cg, r31, kh, true);   // packed; Wn2 perm'd to match
    __syncthreads();   // Wn2 K spans both cg halves
    gemm32_lds<8, 4, 2>(T1, wp + OFF_WN2, cg * 2, bn2, acc, mrow, colbase, r31, kh, lane);

    // out = acc + h (residual)
#pragma unroll
    for (int j = 0; j < 2; ++j)
#pragma unroll
        for (int reg = 0; reg < 16; ++reg) {
            int row = rg * 32 + (reg & 3) + 8 * (reg >> 2) + 4 * kh;
            int gn = n0 + row;
            if (gn < NN) {
                int col = colbase + j * 32 + r31;
                out[(size_t)gn * HD + col] = acc[j][reg] + h[(size_t)gn * HD + col];
            }
        }

    // ---- fused wind finalize (grid-stride; independent of the GEMM above) ----
    for (int tt = blockIdx.x * 512 + tid; tt < NN * LVN; tt += gridDim.x * 512) {
        int nn2 = tt / LVN;
        float c = fmaxf((float)cnt[nn2], 1.f);
        float xu = aggu[tt] / c, xv = aggv[tt] / c;
        aggu[tt] = fminf(fmaxf(xu, -100.f), 100.f);
        aggv[tt] = fminf(fmaxf(xv, -100.f), 100.f);
    }
}

extern "C" void kernel_launch(void* const* d_in, const int* in_sizes, int n_in,
                              void* d_out, int out_size, void* d_ws, size_t ws_size,
                              hipStream_t stream)
{
    const float* h   = (const float*)d_in[0];
    const float* u   = (const float*)d_in[1];
    const float* v   = (const float*)d_in[2];
    const float* ea  = (const float*)d_in[3];
    const float* We1 = (const float*)d_in[4];
    const float* be1 = (const float*)d_in[5];
    const float* We2 = (const float*)d_in[6];
    const float* be2 = (const float*)d_in[7];
    const float* Wn1 = (const float*)d_in[8];
    const float* bn1 = (const float*)d_in[9];
    const float* Wn2 = (const float*)d_in[10];
    const float* bn2 = (const float*)d_in[11];
    const float* Wc1 = (const float*)d_in[12];
    const float* bc1 = (const float*)d_in[13];
    const float* Wcl = (const float*)d_in[14];
    const int*   eidx = (const int*)d_in[15];

    float* out  = (float*)d_out;
    float* agg  = out;                       // [NN,HD]: agg accum, then h_out
    float* aggu = out + (size_t)NN * HD;
    float* aggv = aggu + (size_t)NN * LVN;

    // ---- workspace layout (no overlaps, ~16 MB) ----
    char* p = (char*)d_ws;
    short* wp  = (short*)p;                  p += (size_t)WP_SHORTS * 2;
    int*   off = (int*)p;                    p += (size_t)(NN + 1) * 4;
    p = (char*)(((size_t)p + 15) & ~(size_t)15);
    short* hb  = (short*)p;                  p += (size_t)NN * HD * 2;
    short* uvb = (short*)p;                  p += (size_t)NN * 40 * 2;
    short* latb = (short*)p;                 p += (size_t)NLAT * HD * 2;
    p = (char*)(((size_t)p + 15) & ~(size_t)15);
    int*   rows_r = (int*)p;                 p += (size_t)EE * 4;
    int*   cols_r = (int*)p;                 p += (size_t)EE * 4;
    float* ear    = (float*)p;               p += (size_t)EE * 4;
    p = (char*)(((size_t)p + 15) & ~(size_t)15);
    int*   cnt = (int*)p;                    p += (size_t)NN * 4;
    int*   cur = (int*)p;

    hipMemsetAsync(d_out, 0, (size_t)out_size * sizeof(float), stream);
    hipMemsetAsync(cnt, 0, (size_t)2 * NN * sizeof(int), stream);

    hist_kernel<<<EE / 256, 256, 0, stream>>>(eidx, cnt);
    scan_kernel<<<1, 1024, 0, stream>>>(cnt, off);
    scatter_setup<<<SS_SCAT + SS_HCAST + SS_UV + SS_WP, 256, 0, stream>>>(
        eidx, ea, off, cur, rows_r, cols_r, ear,
        h, hb, u, v, uvb, We1, We2, Wc1, Wcl, Wn1, Wn2, wp);

    edge_mfma<<<EE / 64, 256, 0, stream>>>(hb, uvb, rows_r, cols_r, ear,
                                           be1, be2, bc1, wp, agg, aggu, aggv);

    post_kernel<<<NLAT, 256, 0, stream>>>(agg, latb);

    node_mfma<<<(NN + 127) / 128, 512, 0, stream>>>(hb, h, latb, bn1, bn2, wp,
                                                    agg, aggu, aggv, cnt);
}